// Round 11
// baseline (672.227 us; speedup 1.0000x reference)
//
#include <hip/hip_runtime.h>
#include <hip/hip_bf16.h>

typedef unsigned short u16;
typedef unsigned int u32;

__device__ __forceinline__ float bf2f(u16 h) {
    return __uint_as_float(((u32)h) << 16);
}
__device__ __forceinline__ u16 f2bf(float f) {
    __hip_bfloat16 h = __float2bfloat16(f);   // RNE
    return *reinterpret_cast<u16*>(&h);
}

#define BKT_SHIFT 6
#define BKT_SIZE  64
#define CHUNK     4096   // edges per hist/scatter block (256 thr x 16)

// ---- A1: per-chunk LDS histogram over buckets (dst>>6). No global atomics. ----
__global__ __launch_bounds__(256) void hist_kernel(const int* __restrict__ dst,
                                                   int* __restrict__ hist,
                                                   int E, int nbA, int nbuck) {
    __shared__ int lh[1024];
    for (int j = threadIdx.x; j < nbuck; j += 256) lh[j] = 0;
    __syncthreads();
    int base = blockIdx.x * CHUNK;
    int end  = min(E, base + CHUNK);
    for (int e = base + threadIdx.x; e < end; e += 256)
        atomicAdd(&lh[dst[e] >> BKT_SHIFT], 1);
    __syncthreads();
    for (int j = threadIdx.x; j < nbuck; j += 256)
        hist[j * nbA + blockIdx.x] = lh[j];       // bin-major for the scan
}

// ---- hierarchical scan (generic, int) ----
__global__ __launch_bounds__(256) void scanA_kernel(const int* __restrict__ in,
                                                    int* __restrict__ outp1,
                                                    int* __restrict__ bsum, int n) {
    __shared__ int lds[256];
    int i = blockIdx.x * 256 + threadIdx.x;
    int v = (i < n) ? in[i] : 0;
    lds[threadIdx.x] = v;
    __syncthreads();
    #pragma unroll
    for (int off = 1; off < 256; off <<= 1) {
        int t = (threadIdx.x >= off) ? lds[threadIdx.x - off] : 0;
        __syncthreads();
        lds[threadIdx.x] += t;
        __syncthreads();
    }
    if (i < n) outp1[i + 1] = lds[threadIdx.x];
    if (threadIdx.x == 255) bsum[blockIdx.x] = lds[255];
}
__global__ __launch_bounds__(1024) void scanB_kernel(int* __restrict__ bsum, int nb) {
    __shared__ int lds[1024];
    int t = threadIdx.x;
    int v = (t < nb) ? bsum[t] : 0;
    lds[t] = v;
    __syncthreads();
    #pragma unroll
    for (int off = 1; off < 1024; off <<= 1) {
        int u = (t >= off) ? lds[t - off] : 0;
        __syncthreads();
        lds[t] += u;
        __syncthreads();
    }
    if (t < nb) bsum[t] = lds[t] - v;
}
__global__ __launch_bounds__(256) void scanC_kernel(int* __restrict__ outp1,
                                                    const int* __restrict__ bsum, int n) {
    int i = blockIdx.x * 256 + threadIdx.x;
    if (i < n) outp1[i + 1] += bsum[blockIdx.x];
    if (i == 0) outp1[0] = 0;
}

// ---- A3: scatter edges into bucket-grouped u32 array: src | dloc<<20 ----
__global__ __launch_bounds__(256) void bucket_scatter_kernel(
    const int* __restrict__ src, const int* __restrict__ dst,
    const int* __restrict__ hofs, u32* __restrict__ bucketed,
    int E, int nbA, int nbuck)
{
    __shared__ int lbase[1024];
    __shared__ int lcnt[1024];
    for (int j = threadIdx.x; j < nbuck; j += 256) {
        lbase[j] = hofs[j * nbA + blockIdx.x];
        lcnt[j] = 0;
    }
    __syncthreads();
    int base = blockIdx.x * CHUNK;
    int end  = min(E, base + CHUNK);
    for (int e = base + threadIdx.x; e < end; e += 256) {
        int d = dst[e];
        int b = d >> BKT_SHIFT;
        int r = atomicAdd(&lcnt[b], 1);
        bucketed[lbase[b] + r] = (u32)src[e] | ((u32)(d & (BKT_SIZE - 1)) << 20);
    }
}

// ---- per-bucket degree -> dis ----
__global__ __launch_bounds__(256) void bucketdeg_kernel(
    const u32* __restrict__ bucketed, const int* __restrict__ hofs,
    float* __restrict__ dis, int E, int nbA, int nbuck, int n)
{
    __shared__ int cnt[BKT_SIZE];
    int bkt = blockIdx.x;
    if (threadIdx.x < BKT_SIZE) cnt[threadIdx.x] = 0;
    __syncthreads();
    int estart = hofs[bkt * nbA];
    int eend   = (bkt + 1 < nbuck) ? hofs[(bkt + 1) * nbA] : E;
    for (int e = estart + threadIdx.x; e < eend; e += 256)
        atomicAdd(&cnt[bucketed[e] >> 20], 1);
    __syncthreads();
    if (threadIdx.x < BKT_SIZE) {
        int r = bkt * BKT_SIZE + threadIdx.x;
        if (r < n) {
            int c = cnt[threadIdx.x];
            dis[r] = (c > 0) ? rsqrtf((float)c) : 0.0f;
        }
    }
}

// ---- edge payload: {packed, dis[src]}  (dis[dst] factored into SpMM epilogue) ----
__global__ __launch_bounds__(256) void weight_kernel(const u32* __restrict__ bucketed,
                                                     const float* __restrict__ dis,
                                                     float2* __restrict__ ecolw, int E) {
    int e = blockIdx.x * blockDim.x + threadIdx.x;
    if (e < E) {
        u32 p = bucketed[e];
        ecolw[e] = make_float2(__int_as_float((int)p), dis[p & 0xFFFFFu]);
    }
}

// ---- bucket-parallel SpMM, LDS fp32 accumulation, balanced edge loop ----
// out[r] = dis[r] * sum_e w_src * in[src]  (+addsrc[r]) (+b) (relu)
__global__ __launch_bounds__(256) void spmm_bucket_kernel(
    const u16* __restrict__ in, const u16* __restrict__ addsrc,
    u16* __restrict__ out, const int* __restrict__ hofs,
    const float2* __restrict__ ecolw, const float* __restrict__ dis,
    const float* __restrict__ b, int relu, int E, int nbA, int nbuck, int n)
{
    __shared__ float acc[BKT_SIZE * 16];
    int bkt = blockIdx.x;
    int estart = hofs[bkt * nbA];
    int eend   = (bkt + 1 < nbuck) ? hofs[(bkt + 1) * nbA] : E;
    #pragma unroll
    for (int j = threadIdx.x; j < BKT_SIZE * 16; j += 256) acc[j] = 0.f;
    __syncthreads();

    int g = threadIdx.x >> 2;   // 64 edge-groups
    int q = threadIdx.x & 3;    // feat quarter
    int e = estart + g;
    for (; e + 64 < eend; e += 128) {
        float2 c0 = ecolw[e];
        float2 c1 = ecolw[e + 64];
        u32 p0 = (u32)__float_as_int(c0.x);
        u32 p1 = (u32)__float_as_int(c1.x);
        ushort4 v0 = *((const ushort4*)(in + (size_t)(p0 & 0xFFFFFu) * 16) + q);
        ushort4 v1 = *((const ushort4*)(in + (size_t)(p1 & 0xFFFFFu) * 16) + q);
        float* a0 = acc + (p0 >> 20) * 16 + 4 * q;
        float* a1 = acc + (p1 >> 20) * 16 + 4 * q;
        atomicAdd(a0 + 0, c0.y * bf2f(v0.x));
        atomicAdd(a0 + 1, c0.y * bf2f(v0.y));
        atomicAdd(a0 + 2, c0.y * bf2f(v0.z));
        atomicAdd(a0 + 3, c0.y * bf2f(v0.w));
        atomicAdd(a1 + 0, c1.y * bf2f(v1.x));
        atomicAdd(a1 + 1, c1.y * bf2f(v1.y));
        atomicAdd(a1 + 2, c1.y * bf2f(v1.z));
        atomicAdd(a1 + 3, c1.y * bf2f(v1.w));
    }
    if (e < eend) {
        float2 c0 = ecolw[e];
        u32 p0 = (u32)__float_as_int(c0.x);
        ushort4 v0 = *((const ushort4*)(in + (size_t)(p0 & 0xFFFFFu) * 16) + q);
        float* a0 = acc + (p0 >> 20) * 16 + 4 * q;
        atomicAdd(a0 + 0, c0.y * bf2f(v0.x));
        atomicAdd(a0 + 1, c0.y * bf2f(v0.y));
        atomicAdd(a0 + 2, c0.y * bf2f(v0.z));
        atomicAdd(a0 + 3, c0.y * bf2f(v0.w));
    }
    __syncthreads();

    // epilogue: 64 rows x 16 feats, one (row, feat-quarter) per thread
    int row = threadIdx.x >> 2;
    int qq  = threadIdx.x & 3;
    int r   = bkt * BKT_SIZE + row;
    if (r < n) {
        float dr = dis[r];
        const float* ap = acc + row * 16 + 4 * qq;
        float Ax = ap[0] * dr, Ay = ap[1] * dr, Az = ap[2] * dr, Aw = ap[3] * dr;
        if (addsrc) {
            ushort4 s = *((const ushort4*)(addsrc + (size_t)r * 16) + qq);
            Ax += bf2f(s.x); Ay += bf2f(s.y); Az += bf2f(s.z); Aw += bf2f(s.w);
        }
        if (b) {
            float4 bb = *((const float4*)b + qq);
            Ax += bb.x; Ay += bb.y; Az += bb.z; Aw += bb.w;
        }
        if (relu) {
            Ax = fmaxf(Ax, 0.f); Ay = fmaxf(Ay, 0.f);
            Az = fmaxf(Az, 0.f); Aw = fmaxf(Aw, 0.f);
        }
        ushort4 o; o.x = f2bf(Ax); o.y = f2bf(Ay); o.z = f2bf(Az); o.w = f2bf(Aw);
        *((ushort4*)(out + (size_t)r * 16) + qq) = o;
    }
}

// ---- GEMM1 (tiled, bf16 planes out): z_k = rownorm(x) @ W1[k] ----
__global__ __launch_bounds__(256) void gemm1_bf_kernel(
    const float* __restrict__ x, const float* __restrict__ W1,
    u16* __restrict__ zb, int n, int nstride)
{
    __shared__ float As[64 * 132];
    __shared__ float Bs[64 * 64];
    __shared__ float sums[128];
    const int t  = threadIdx.x;
    const int tx = t & 15;
    const int ty = t >> 4;
    const int c  = t & 15;
    const int g  = t >> 4;
    const int block_row = blockIdx.x * 128;

    float acc[8][4];
    #pragma unroll
    for (int i = 0; i < 8; ++i)
        #pragma unroll
        for (int j = 0; j < 4; ++j) acc[i][j] = 0.f;

    for (int kp = 0; kp < 2; ++kp) {
        #pragma unroll
        for (int i = 0; i < 8; ++i) {
            int row  = g + 16 * i;
            int grow = block_row + row;
            float v0 = 0.f, v1 = 0.f, v2 = 0.f, v3 = 0.f;
            if (grow < n) {
                const float* xp = x + (long)grow * 128 + kp * 64 + c;
                v0 = xp[0]; v1 = xp[16]; v2 = xp[32]; v3 = xp[48];
            }
            As[(c +  0) * 132 + row] = v0;
            As[(c + 16) * 132 + row] = v1;
            As[(c + 32) * 132 + row] = v2;
            As[(c + 48) * 132 + row] = v3;
            float red = (v0 + v1) + (v2 + v3);
            #pragma unroll
            for (int off = 8; off > 0; off >>= 1) red += __shfl_down(red, off, 16);
            if (c == 0) { if (kp == 0) sums[row] = red; else sums[row] += red; }
        }
        #pragma unroll
        for (int i2 = 0; i2 < 4; ++i2) {
            int kk = g + 16 * i2;
            int kglob = kp * 64 + kk;
            float4 wv = *(const float4*)(W1 + (c >> 2) * 2048 + kglob * 16 + 4 * (c & 3));
            *(float4*)(Bs + kk * 64 + 4 * c) = wv;
        }
        __syncthreads();
        #pragma unroll 4
        for (int kk = 0; kk < 64; ++kk) {
            float4 a0 = *(const float4*)(As + kk * 132 + 8 * ty);
            float4 a1 = *(const float4*)(As + kk * 132 + 8 * ty + 4);
            float4 bv = *(const float4*)(Bs + kk * 64 + 4 * tx);
            float ar[8] = {a0.x, a0.y, a0.z, a0.w, a1.x, a1.y, a1.z, a1.w};
            float br[4] = {bv.x, bv.y, bv.z, bv.w};
            #pragma unroll
            for (int i = 0; i < 8; ++i)
                #pragma unroll
                for (int j = 0; j < 4; ++j)
                    acc[i][j] += ar[i] * br[j];
        }
        __syncthreads();
    }
    int plane = tx >> 2;
    int oo4   = 4 * (tx & 3);
    #pragma unroll
    for (int i = 0; i < 8; ++i) {
        int row  = 8 * ty + i;
        int grow = block_row + row;
        if (grow < n) {
            float s = 1.0f / fmaxf(sums[row], 1e-8f);
            ushort4 o;
            o.x = f2bf(acc[i][0] * s); o.y = f2bf(acc[i][1] * s);
            o.z = f2bf(acc[i][2] * s); o.w = f2bf(acc[i][3] * s);
            *(ushort4*)(zb + (long)plane * nstride + (long)grow * 16 + oo4) = o;
        }
    }
}

// ---- GEMM2 (tiled, bf16 planes in, fp32 out): out = cat(G0..G3) @ W2cat + b2 ----
__global__ __launch_bounds__(256) void gemm2_bf_kernel(
    const u16* __restrict__ zb, const float* __restrict__ W2,
    const float* __restrict__ b2, float* __restrict__ out, int n, int nstride)
{
    __shared__ float As[64 * 132];
    __shared__ float Bs[64 * 64];
    const int t  = threadIdx.x;
    const int tx = t & 15;
    const int ty = t >> 4;
    const int c  = t & 15;
    const int g  = t >> 4;
    const int block_row = blockIdx.x * 128;

    float acc[8][4];
    #pragma unroll
    for (int i = 0; i < 8; ++i)
        #pragma unroll
        for (int j = 0; j < 4; ++j) acc[i][j] = 0.f;

    #pragma unroll
    for (int i = 0; i < 8; ++i) {
        int row  = g + 16 * i;
        int grow = block_row + row;
        float v0 = 0.f, v1 = 0.f, v2 = 0.f, v3 = 0.f;
        if (grow < n) {
            const u16* zp = zb + (long)grow * 16 + c;
            v0 = bf2f(zp[0]);
            v1 = bf2f(zp[(long)nstride]);
            v2 = bf2f(zp[2 * (long)nstride]);
            v3 = bf2f(zp[3 * (long)nstride]);
        }
        As[(c +  0) * 132 + row] = v0;
        As[(c + 16) * 132 + row] = v1;
        As[(c + 32) * 132 + row] = v2;
        As[(c + 48) * 132 + row] = v3;
    }
    #pragma unroll
    for (int i2 = 0; i2 < 4; ++i2) {
        int j = g + 16 * i2;
        float4 wv = *(const float4*)(W2 + j * 64 + 4 * c);
        *(float4*)(Bs + j * 64 + 4 * c) = wv;
    }
    __syncthreads();
    #pragma unroll 4
    for (int kk = 0; kk < 64; ++kk) {
        float4 a0 = *(const float4*)(As + kk * 132 + 8 * ty);
        float4 a1 = *(const float4*)(As + kk * 132 + 8 * ty + 4);
        float4 bv = *(const float4*)(Bs + kk * 64 + 4 * tx);
        float ar[8] = {a0.x, a0.y, a0.z, a0.w, a1.x, a1.y, a1.z, a1.w};
        float br[4] = {bv.x, bv.y, bv.z, bv.w};
        #pragma unroll
        for (int i = 0; i < 8; ++i)
            #pragma unroll
            for (int j = 0; j < 4; ++j)
                acc[i][j] += ar[i] * br[j];
    }
    float4 bias = *(const float4*)(b2 + 4 * tx);
    #pragma unroll
    for (int i = 0; i < 8; ++i) {
        int grow = block_row + 8 * ty + i;
        if (grow < n) {
            float4 o = make_float4(acc[i][0] + bias.x, acc[i][1] + bias.y,
                                   acc[i][2] + bias.z, acc[i][3] + bias.w);
            *(float4*)(out + (long)grow * 64 + 4 * tx) = o;
        }
    }
}

// ================= fp32 fallback path (small workspace or odd shapes) =================
__global__ void deg_kernel(const int* __restrict__ dst, float* __restrict__ deg, int E) {
    int e = blockIdx.x * blockDim.x + threadIdx.x;
    if (e < E) atomicAdd(&deg[dst[e]], 1.0f);
}
__global__ void disf_kernel(float* __restrict__ deg, int n) {
    int i = blockIdx.x * blockDim.x + threadIdx.x;
    if (i < n) {
        float d = deg[i];
        deg[i] = (d > 0.0f) ? rsqrtf(d) : 0.0f;
    }
}
__global__ __launch_bounds__(256) void gemm1_f32_kernel(
    const float* __restrict__ x, const float* __restrict__ W1,
    float* __restrict__ z, int n, int nstride)
{
    __shared__ float As[64 * 132];
    __shared__ float Bs[64 * 64];
    __shared__ float sums[128];
    const int t  = threadIdx.x;
    const int tx = t & 15;
    const int ty = t >> 4;
    const int c  = t & 15;
    const int g  = t >> 4;
    const int block_row = blockIdx.x * 128;
    float acc[8][4];
    #pragma unroll
    for (int i = 0; i < 8; ++i)
        #pragma unroll
        for (int j = 0; j < 4; ++j) acc[i][j] = 0.f;
    for (int kp = 0; kp < 2; ++kp) {
        #pragma unroll
        for (int i = 0; i < 8; ++i) {
            int row  = g + 16 * i;
            int grow = block_row + row;
            float v0 = 0.f, v1 = 0.f, v2 = 0.f, v3 = 0.f;
            if (grow < n) {
                const float* xp = x + (long)grow * 128 + kp * 64 + c;
                v0 = xp[0]; v1 = xp[16]; v2 = xp[32]; v3 = xp[48];
            }
            As[(c +  0) * 132 + row] = v0;
            As[(c + 16) * 132 + row] = v1;
            As[(c + 32) * 132 + row] = v2;
            As[(c + 48) * 132 + row] = v3;
            float red = (v0 + v1) + (v2 + v3);
            #pragma unroll
            for (int off = 8; off > 0; off >>= 1) red += __shfl_down(red, off, 16);
            if (c == 0) { if (kp == 0) sums[row] = red; else sums[row] += red; }
        }
        #pragma unroll
        for (int i2 = 0; i2 < 4; ++i2) {
            int kk = g + 16 * i2;
            int kglob = kp * 64 + kk;
            float4 wv = *(const float4*)(W1 + (c >> 2) * 2048 + kglob * 16 + 4 * (c & 3));
            *(float4*)(Bs + kk * 64 + 4 * c) = wv;
        }
        __syncthreads();
        #pragma unroll 4
        for (int kk = 0; kk < 64; ++kk) {
            float4 a0 = *(const float4*)(As + kk * 132 + 8 * ty);
            float4 a1 = *(const float4*)(As + kk * 132 + 8 * ty + 4);
            float4 bv = *(const float4*)(Bs + kk * 64 + 4 * tx);
            float ar[8] = {a0.x, a0.y, a0.z, a0.w, a1.x, a1.y, a1.z, a1.w};
            float br[4] = {bv.x, bv.y, bv.z, bv.w};
            #pragma unroll
            for (int i = 0; i < 8; ++i)
                #pragma unroll
                for (int j = 0; j < 4; ++j)
                    acc[i][j] += ar[i] * br[j];
        }
        __syncthreads();
    }
    int plane = tx >> 2;
    int oo4   = 4 * (tx & 3);
    #pragma unroll
    for (int i = 0; i < 8; ++i) {
        int row  = 8 * ty + i;
        int grow = block_row + row;
        if (grow < n) {
            float s = 1.0f / fmaxf(sums[row], 1e-8f);
            float4 o = make_float4(acc[i][0] * s, acc[i][1] * s, acc[i][2] * s, acc[i][3] * s);
            *(float4*)(z + (long)plane * nstride + (long)grow * 16 + oo4) = o;
        }
    }
}
__global__ __launch_bounds__(256) void spmm_atomic_kernel(
    const float* __restrict__ in, float* __restrict__ out,
    const int* __restrict__ src, const int* __restrict__ dst,
    const float* __restrict__ dis, int E)
{
    int t = blockIdx.x * blockDim.x + threadIdx.x;
    int e = t >> 4, f = t & 15;
    if (e < E) {
        int s = src[e], d = dst[e];
        atomicAdd(&out[d * 16 + f], dis[s] * dis[d] * in[s * 16 + f]);
    }
}
__global__ void bias_relu_kernel(float* __restrict__ z0, const float* __restrict__ b, int total) {
    int i = blockIdx.x * blockDim.x + threadIdx.x;
    if (i < total) {
        float v = z0[i] + b[i & 15];
        z0[i] = v > 0.0f ? v : 0.0f;
    }
}
__global__ __launch_bounds__(256) void gemm2_f32_kernel(
    const float* __restrict__ z, const float* __restrict__ W2,
    const float* __restrict__ b2, float* __restrict__ out, int n, int nstride)
{
    __shared__ float As[64 * 132];
    __shared__ float Bs[64 * 64];
    const int t  = threadIdx.x;
    const int tx = t & 15;
    const int ty = t >> 4;
    const int c  = t & 15;
    const int g  = t >> 4;
    const int block_row = blockIdx.x * 128;
    float acc[8][4];
    #pragma unroll
    for (int i = 0; i < 8; ++i)
        #pragma unroll
        for (int j = 0; j < 4; ++j) acc[i][j] = 0.f;
    #pragma unroll
    for (int i = 0; i < 8; ++i) {
        int row  = g + 16 * i;
        int grow = block_row + row;
        float v0 = 0.f, v1 = 0.f, v2 = 0.f, v3 = 0.f;
        if (grow < n) {
            const float* zp = z + (long)grow * 16 + c;
            v0 = zp[0];
            v1 = zp[(long)nstride];
            v2 = zp[2 * (long)nstride];
            v3 = zp[3 * (long)nstride];
        }
        As[(c +  0) * 132 + row] = v0;
        As[(c + 16) * 132 + row] = v1;
        As[(c + 32) * 132 + row] = v2;
        As[(c + 48) * 132 + row] = v3;
    }
    #pragma unroll
    for (int i2 = 0; i2 < 4; ++i2) {
        int j = g + 16 * i2;
        float4 wv = *(const float4*)(W2 + j * 64 + 4 * c);
        *(float4*)(Bs + j * 64 + 4 * c) = wv;
    }
    __syncthreads();
    #pragma unroll 4
    for (int kk = 0; kk < 64; ++kk) {
        float4 a0 = *(const float4*)(As + kk * 132 + 8 * ty);
        float4 a1 = *(const float4*)(As + kk * 132 + 8 * ty + 4);
        float4 bv = *(const float4*)(Bs + kk * 64 + 4 * tx);
        float ar[8] = {a0.x, a0.y, a0.z, a0.w, a1.x, a1.y, a1.z, a1.w};
        float br[4] = {bv.x, bv.y, bv.z, bv.w};
        #pragma unroll
        for (int i = 0; i < 8; ++i)
            #pragma unroll
            for (int j = 0; j < 4; ++j)
                acc[i][j] += ar[i] * br[j];
    }
    float4 bias = *(const float4*)(b2 + 4 * tx);
    #pragma unroll
    for (int i = 0; i < 8; ++i) {
        int grow = block_row + 8 * ty + i;
        if (grow < n) {
            float4 o = make_float4(acc[i][0] + bias.x, acc[i][1] + bias.y,
                                   acc[i][2] + bias.z, acc[i][3] + bias.w);
            *(float4*)(out + (long)grow * 64 + 4 * tx) = o;
        }
    }
}

static inline size_t align16(size_t v) { return (v + 15) & ~(size_t)15; }

extern "C" void kernel_launch(void* const* d_in, const int* in_sizes, int n_in,
                              void* d_out, int out_size, void* d_ws, size_t ws_size,
                              hipStream_t stream) {
    const float* x   = (const float*)d_in[0];
    const int*   ei  = (const int*)d_in[1];
    const float* W1  = (const float*)d_in[2];
    const float* b1  = (const float*)d_in[3];
    const float* W2  = (const float*)d_in[4];
    const float* bb2 = (const float*)d_in[5];
    float* out = (float*)d_out;

    const int n  = in_sizes[0] / 128;   // 50000
    const int E  = in_sizes[1] / 2;     // 800000
    const int NS = n * 16;

    const int* srcp = ei;
    const int* dstp = ei + E;

    const int nbuck = (n + BKT_SIZE - 1) >> BKT_SHIFT;         // 782
    const int nbA   = (E + CHUNK - 1) / CHUNK;                 // 196
    const int m     = nbuck * nbA;                             // ~153k
    const int nbS   = (m + 255) / 256;                         // scan blocks (~599)

    char* wsb = (char*)d_ws;
    // bytes: hist[m] | hofs[m+1] | bsum[1024] | dis[n] | zb[4*NS u16] | bucketed[E u32] | ecolw[E f2]
    int*   hist   = (int*)wsb;
    int*   hofs   = (int*)(wsb + (size_t)4 * m);
    int*   bsum   = (int*)(wsb + (size_t)4 * (2 * m + 1));
    float* dis    = (float*)(wsb + (size_t)4 * (2 * m + 1 + 1024));
    size_t zoffb  = align16((size_t)4 * (2 * m + 1 + 1024 + n));
    u16*   zb     = (u16*)(wsb + zoffb);
    size_t bkoff  = align16(zoffb + (size_t)2 * 4 * NS);
    u32*   bucketed = (u32*)(wsb + bkoff);
    size_t ecooff = align16(bkoff + (size_t)4 * E);
    float2* ecolw = (float2*)(wsb + ecooff);
    size_t need   = ecooff + (size_t)8 * E;

    int gemm_blocks = (n + 127) / 128;

    if (ws_size >= need && n < (1 << 20) && nbuck <= 1024 && nbS <= 1024) {
        // ---------- bucket build (zero global atomics) ----------
        hist_kernel<<<nbA, 256, 0, stream>>>(dstp, hist, E, nbA, nbuck);
        scanA_kernel<<<nbS, 256, 0, stream>>>(hist, hofs, bsum, m);
        scanB_kernel<<<1, 1024, 0, stream>>>(bsum, nbS);
        scanC_kernel<<<nbS, 256, 0, stream>>>(hofs, bsum, m);
        bucket_scatter_kernel<<<nbA, 256, 0, stream>>>(srcp, dstp, hofs, bucketed, E, nbA, nbuck);
        bucketdeg_kernel<<<nbuck, 256, 0, stream>>>(bucketed, hofs, dis, E, nbA, nbuck, n);
        weight_kernel<<<(E + 255) / 256, 256, 0, stream>>>(bucketed, dis, ecolw, E);

        gemm1_bf_kernel<<<gemm_blocks, 256, 0, stream>>>(x, W1, zb, n, NS);

        // layer-1 Horner
        spmm_bucket_kernel<<<nbuck, 256, 0, stream>>>(zb + 3 * NS, zb + 2 * NS, zb + 2 * NS, hofs, ecolw, dis, nullptr, 0, E, nbA, nbuck, n);
        spmm_bucket_kernel<<<nbuck, 256, 0, stream>>>(zb + 2 * NS, zb + 1 * NS, zb + 1 * NS, hofs, ecolw, dis, nullptr, 0, E, nbA, nbuck, n);
        spmm_bucket_kernel<<<nbuck, 256, 0, stream>>>(zb + 1 * NS, zb,          zb,          hofs, ecolw, dis, b1,      1, E, nbA, nbuck, n);
        // layer-2 hops
        spmm_bucket_kernel<<<nbuck, 256, 0, stream>>>(zb,          nullptr, zb + 1 * NS, hofs, ecolw, dis, nullptr, 0, E, nbA, nbuck, n);
        spmm_bucket_kernel<<<nbuck, 256, 0, stream>>>(zb + 1 * NS, nullptr, zb + 2 * NS, hofs, ecolw, dis, nullptr, 0, E, nbA, nbuck, n);
        spmm_bucket_kernel<<<nbuck, 256, 0, stream>>>(zb + 2 * NS, nullptr, zb + 3 * NS, hofs, ecolw, dis, nullptr, 0, E, nbA, nbuck, n);

        gemm2_bf_kernel<<<gemm_blocks, 256, 0, stream>>>(zb, W2, bb2, out, n, NS);
    } else {
        // ---------- fp32 atomic fallback ----------
        float* ws = (float*)d_ws;
        float* dis2 = ws;
        size_t z2off = ((size_t)n + 3) & ~(size_t)3;
        float* z2 = ws + z2off;
        hipMemsetAsync(dis2, 0, n * sizeof(float), stream);
        deg_kernel<<<(E + 255) / 256, 256, 0, stream>>>(dstp, dis2, E);
        disf_kernel<<<(n + 255) / 256, 256, 0, stream>>>(dis2, n);
        gemm1_f32_kernel<<<gemm_blocks, 256, 0, stream>>>(x, W1, z2, n, NS);
        int sb = (16 * E + 255) / 256;
        spmm_atomic_kernel<<<sb, 256, 0, stream>>>(z2 + 3 * NS, z2 + 2 * NS, srcp, dstp, dis2, E);
        spmm_atomic_kernel<<<sb, 256, 0, stream>>>(z2 + 2 * NS, z2 + 1 * NS, srcp, dstp, dis2, E);
        spmm_atomic_kernel<<<sb, 256, 0, stream>>>(z2 + 1 * NS, z2,          srcp, dstp, dis2, E);
        bias_relu_kernel<<<(NS + 255) / 256, 256, 0, stream>>>(z2, b1, NS);
        hipMemsetAsync(z2 + NS, 0, (size_t)3 * NS * sizeof(float), stream);
        spmm_atomic_kernel<<<sb, 256, 0, stream>>>(z2,          z2 + NS,     srcp, dstp, dis2, E);
        spmm_atomic_kernel<<<sb, 256, 0, stream>>>(z2 + NS,     z2 + 2 * NS, srcp, dstp, dis2, E);
        spmm_atomic_kernel<<<sb, 256, 0, stream>>>(z2 + 2 * NS, z2 + 3 * NS, srcp, dstp, dis2, E);
        gemm2_f32_kernel<<<gemm_blocks, 256, 0, stream>>>(z2, W2, bb2, out, n, NS);
    }
}

// Round 12
// 215.342 us; speedup vs baseline: 3.1217x; 3.1217x over previous
//
#include <hip/hip_runtime.h>
#include <hip/hip_bf16.h>

typedef unsigned short u16;

__device__ __forceinline__ float bf2f(u16 h) {
    return __uint_as_float(((unsigned int)h) << 16);
}
__device__ __forceinline__ u16 f2bf(float f) {
    __hip_bfloat16 h = __float2bfloat16(f);   // RNE
    return *reinterpret_cast<u16*>(&h);
}

#define BKT_SHIFT 7
#define BKT_SIZE  128
#define CHUNK     2048   // edges per hist/scatter block (256 thr x 8)

// ---- A1: per-chunk LDS histogram over buckets (dst>>7). No global atomics. ----
__global__ __launch_bounds__(256) void hist_kernel(const int* __restrict__ dst,
                                                   int* __restrict__ hist,
                                                   int E, int nbA, int nbuck) {
    __shared__ int lh[512];
    for (int j = threadIdx.x; j < nbuck; j += 256) lh[j] = 0;
    __syncthreads();
    int base = blockIdx.x * CHUNK;
    int end  = min(E, base + CHUNK);
    for (int e = base + threadIdx.x; e < end; e += 256)
        atomicAdd(&lh[dst[e] >> BKT_SHIFT], 1);
    __syncthreads();
    for (int j = threadIdx.x; j < nbuck; j += 256)
        hist[j * nbA + blockIdx.x] = lh[j];       // bin-major for the scan
}

// ---- hierarchical scan (generic, int) ----
__global__ __launch_bounds__(256) void scanA_kernel(const int* __restrict__ in,
                                                    int* __restrict__ outp1,
                                                    int* __restrict__ bsum, int n) {
    __shared__ int lds[256];
    int i = blockIdx.x * 256 + threadIdx.x;
    int v = (i < n) ? in[i] : 0;
    lds[threadIdx.x] = v;
    __syncthreads();
    #pragma unroll
    for (int off = 1; off < 256; off <<= 1) {
        int t = (threadIdx.x >= off) ? lds[threadIdx.x - off] : 0;
        __syncthreads();
        lds[threadIdx.x] += t;
        __syncthreads();
    }
    if (i < n) outp1[i + 1] = lds[threadIdx.x];
    if (threadIdx.x == 255) bsum[blockIdx.x] = lds[255];
}
__global__ __launch_bounds__(1024) void scanB_kernel(int* __restrict__ bsum, int nb) {
    __shared__ int lds[1024];
    int t = threadIdx.x;
    int v = (t < nb) ? bsum[t] : 0;
    lds[t] = v;
    __syncthreads();
    #pragma unroll
    for (int off = 1; off < 1024; off <<= 1) {
        int u = (t >= off) ? lds[t - off] : 0;
        __syncthreads();
        lds[t] += u;
        __syncthreads();
    }
    if (t < nb) bsum[t] = lds[t] - v;
}
__global__ __launch_bounds__(256) void scanC_kernel(int* __restrict__ outp1,
                                                    const int* __restrict__ bsum, int n) {
    int i = blockIdx.x * 256 + threadIdx.x;
    if (i < n) outp1[i + 1] += bsum[blockIdx.x];
    if (i == 0) outp1[0] = 0;
}

// ---- A3: scatter edges into bucket-grouped array (LDS-atomic local ranks) ----
__global__ __launch_bounds__(256) void bucket_scatter_kernel(
    const int* __restrict__ src, const int* __restrict__ dst,
    const int* __restrict__ hofs, int2* __restrict__ bucketed,
    int E, int nbA, int nbuck)
{
    __shared__ int lbase[512];
    __shared__ int lcnt[512];
    for (int j = threadIdx.x; j < nbuck; j += 256) {
        lbase[j] = hofs[j * nbA + blockIdx.x];
        lcnt[j] = 0;
    }
    __syncthreads();
    int base = blockIdx.x * CHUNK;
    int end  = min(E, base + CHUNK);
    for (int e = base + threadIdx.x; e < end; e += 256) {
        int d = dst[e];
        int b = d >> BKT_SHIFT;
        int r = atomicAdd(&lcnt[b], 1);
        bucketed[lbase[b] + r] = make_int2(src[e], d);
    }
}

// ---- B: one block per bucket -> rowptr, dis, ecolw (weight = dis_dst staged) ----
__global__ __launch_bounds__(256) void csr_finalize_kernel(
    const int2* __restrict__ bucketed, const int* __restrict__ hofs,
    int* __restrict__ rowptr, float* __restrict__ dis,
    float2* __restrict__ ecolw, int E, int nbA, int nbuck, int n)
{
    __shared__ int cnt[BKT_SIZE];
    __shared__ int run[BKT_SIZE];
    __shared__ float disl[BKT_SIZE];
    int b = blockIdx.x;
    int bstart = hofs[b * nbA];
    int bend   = (b == nbuck - 1) ? E : hofs[(b + 1) * nbA];
    for (int j = threadIdx.x; j < BKT_SIZE; j += 256) cnt[j] = 0;
    __syncthreads();
    for (int i = bstart + threadIdx.x; i < bend; i += 256)
        atomicAdd(&cnt[bucketed[i].y & (BKT_SIZE - 1)], 1);
    __syncthreads();
    if (threadIdx.x == 0) {
        int runacc = 0;
        for (int j = 0; j < BKT_SIZE; ++j) {
            int c = cnt[j];
            run[j] = runacc;          // exclusive prefix (local)
            runacc += c;
        }
    }
    __syncthreads();
    for (int j = threadIdx.x; j < BKT_SIZE; j += 256) {
        int d = b * BKT_SIZE + j;
        if (d < n) {
            rowptr[d] = bstart + run[j];
            int c = cnt[j];
            float dv = (c > 0) ? rsqrtf((float)c) : 0.0f;
            dis[d] = dv;
            disl[j] = dv;
        }
    }
    if (b == 0 && threadIdx.x == 0) rowptr[n] = E;
    __syncthreads();
    for (int i = bstart + threadIdx.x; i < bend; i += 256) {
        int2 p = bucketed[i];
        int j = p.y & (BKT_SIZE - 1);
        int r = atomicAdd(&run[j], 1);
        ecolw[bstart + r] = make_float2(__int_as_float(p.x), disl[j]);
    }
}

// ---- W: ecolw[e].y = staged dis_dst * dis[src] (the one random gather pass) ----
__global__ __launch_bounds__(256) void weight_kernel(float2* __restrict__ ecolw,
                                                     const float* __restrict__ dis, int E) {
    int e = blockIdx.x * blockDim.x + threadIdx.x;
    if (e < E) {
        float2 c = ecolw[e];
        ecolw[e].y = c.y * dis[__float_as_int(c.x)];
    }
}

// ---- GEMM1 (tiled, bf16 planes out): z_k = rownorm(x) @ W1[k] ----
__global__ __launch_bounds__(256) void gemm1_bf_kernel(
    const float* __restrict__ x, const float* __restrict__ W1,
    u16* __restrict__ zb, int n, int nstride)
{
    __shared__ float As[64 * 132];
    __shared__ float Bs[64 * 64];
    __shared__ float sums[128];
    const int t  = threadIdx.x;
    const int tx = t & 15;
    const int ty = t >> 4;
    const int c  = t & 15;
    const int g  = t >> 4;
    const int block_row = blockIdx.x * 128;

    float acc[8][4];
    #pragma unroll
    for (int i = 0; i < 8; ++i)
        #pragma unroll
        for (int j = 0; j < 4; ++j) acc[i][j] = 0.f;

    for (int kp = 0; kp < 2; ++kp) {
        #pragma unroll
        for (int i = 0; i < 8; ++i) {
            int row  = g + 16 * i;
            int grow = block_row + row;
            float v0 = 0.f, v1 = 0.f, v2 = 0.f, v3 = 0.f;
            if (grow < n) {
                const float* xp = x + (long)grow * 128 + kp * 64 + c;
                v0 = xp[0]; v1 = xp[16]; v2 = xp[32]; v3 = xp[48];
            }
            As[(c +  0) * 132 + row] = v0;
            As[(c + 16) * 132 + row] = v1;
            As[(c + 32) * 132 + row] = v2;
            As[(c + 48) * 132 + row] = v3;
            float red = (v0 + v1) + (v2 + v3);
            #pragma unroll
            for (int off = 8; off > 0; off >>= 1) red += __shfl_down(red, off, 16);
            if (c == 0) { if (kp == 0) sums[row] = red; else sums[row] += red; }
        }
        #pragma unroll
        for (int i2 = 0; i2 < 4; ++i2) {
            int kk = g + 16 * i2;
            int kglob = kp * 64 + kk;
            float4 wv = *(const float4*)(W1 + (c >> 2) * 2048 + kglob * 16 + 4 * (c & 3));
            *(float4*)(Bs + kk * 64 + 4 * c) = wv;
        }
        __syncthreads();
        #pragma unroll 4
        for (int kk = 0; kk < 64; ++kk) {
            float4 a0 = *(const float4*)(As + kk * 132 + 8 * ty);
            float4 a1 = *(const float4*)(As + kk * 132 + 8 * ty + 4);
            float4 bv = *(const float4*)(Bs + kk * 64 + 4 * tx);
            float ar[8] = {a0.x, a0.y, a0.z, a0.w, a1.x, a1.y, a1.z, a1.w};
            float br[4] = {bv.x, bv.y, bv.z, bv.w};
            #pragma unroll
            for (int i = 0; i < 8; ++i)
                #pragma unroll
                for (int j = 0; j < 4; ++j)
                    acc[i][j] += ar[i] * br[j];
        }
        __syncthreads();
    }
    int plane = tx >> 2;
    int oo4   = 4 * (tx & 3);
    #pragma unroll
    for (int i = 0; i < 8; ++i) {
        int row  = 8 * ty + i;
        int grow = block_row + row;
        if (grow < n) {
            float s = 1.0f / fmaxf(sums[row], 1e-8f);
            ushort4 o;
            o.x = f2bf(acc[i][0] * s); o.y = f2bf(acc[i][1] * s);
            o.z = f2bf(acc[i][2] * s); o.w = f2bf(acc[i][3] * s);
            *(ushort4*)(zb + (long)plane * nstride + (long)grow * 16 + oo4) = o;
        }
    }
}

// ---- CSR SpMM on bf16 planes: 8 lanes/row (2 feats each), fp32 accumulate ----
// vs R10: 4->8 lanes/row doubles resident waves (12->24/CU) for this
// latency-bound gather loop; same bytes, same coalescing (8x4B contiguous).
__global__ __launch_bounds__(256) void spmm_csr_bf_kernel(
    const u16* __restrict__ in, const u16* __restrict__ addsrc,
    u16* __restrict__ out, const int* __restrict__ rowptr,
    const float2* __restrict__ ecolw, const float* __restrict__ b,
    int relu, int n)
{
    int t = blockIdx.x * blockDim.x + threadIdx.x;
    int r = t >> 3, q = t & 7;
    if (r >= n) return;
    int e0 = rowptr[r], e1 = rowptr[r + 1];
    float ax0=0,ay0=0, ax1=0,ay1=0, ax2=0,ay2=0, ax3=0,ay3=0;
    int e = e0;
    for (; e + 4 <= e1; e += 4) {
        float2 c0 = ecolw[e], c1 = ecolw[e+1], c2 = ecolw[e+2], c3 = ecolw[e+3];
        ushort2 v0 = *((const ushort2*)(in + (size_t)__float_as_int(c0.x) * 16) + q);
        ushort2 v1 = *((const ushort2*)(in + (size_t)__float_as_int(c1.x) * 16) + q);
        ushort2 v2 = *((const ushort2*)(in + (size_t)__float_as_int(c2.x) * 16) + q);
        ushort2 v3 = *((const ushort2*)(in + (size_t)__float_as_int(c3.x) * 16) + q);
        ax0 += c0.y * bf2f(v0.x); ay0 += c0.y * bf2f(v0.y);
        ax1 += c1.y * bf2f(v1.x); ay1 += c1.y * bf2f(v1.y);
        ax2 += c2.y * bf2f(v2.x); ay2 += c2.y * bf2f(v2.y);
        ax3 += c3.y * bf2f(v3.x); ay3 += c3.y * bf2f(v3.y);
    }
    for (; e < e1; ++e) {
        float2 c0 = ecolw[e];
        ushort2 v0 = *((const ushort2*)(in + (size_t)__float_as_int(c0.x) * 16) + q);
        ax0 += c0.y * bf2f(v0.x); ay0 += c0.y * bf2f(v0.y);
    }
    float Ax = (ax0 + ax1) + (ax2 + ax3);
    float Ay = (ay0 + ay1) + (ay2 + ay3);
    if (addsrc) {
        ushort2 s = *((const ushort2*)(addsrc + (size_t)r * 16) + q);
        Ax += bf2f(s.x); Ay += bf2f(s.y);
    }
    if (b) {
        Ax += b[2 * q];
        Ay += b[2 * q + 1];
    }
    if (relu) {
        Ax = fmaxf(Ax, 0.f);
        Ay = fmaxf(Ay, 0.f);
    }
    ushort2 o; o.x = f2bf(Ax); o.y = f2bf(Ay);
    *((ushort2*)(out + (size_t)r * 16) + q) = o;
}

// ---- GEMM2 (tiled, bf16 planes in, fp32 out): out = cat(G0..G3) @ W2cat + b2 ----
__global__ __launch_bounds__(256) void gemm2_bf_kernel(
    const u16* __restrict__ zb, const float* __restrict__ W2,
    const float* __restrict__ b2, float* __restrict__ out, int n, int nstride)
{
    __shared__ float As[64 * 132];
    __shared__ float Bs[64 * 64];
    const int t  = threadIdx.x;
    const int tx = t & 15;
    const int ty = t >> 4;
    const int c  = t & 15;
    const int g  = t >> 4;
    const int block_row = blockIdx.x * 128;

    float acc[8][4];
    #pragma unroll
    for (int i = 0; i < 8; ++i)
        #pragma unroll
        for (int j = 0; j < 4; ++j) acc[i][j] = 0.f;

    #pragma unroll
    for (int i = 0; i < 8; ++i) {
        int row  = g + 16 * i;
        int grow = block_row + row;
        float v0 = 0.f, v1 = 0.f, v2 = 0.f, v3 = 0.f;
        if (grow < n) {
            const u16* zp = zb + (long)grow * 16 + c;
            v0 = bf2f(zp[0]);
            v1 = bf2f(zp[(long)nstride]);
            v2 = bf2f(zp[2 * (long)nstride]);
            v3 = bf2f(zp[3 * (long)nstride]);
        }
        As[(c +  0) * 132 + row] = v0;
        As[(c + 16) * 132 + row] = v1;
        As[(c + 32) * 132 + row] = v2;
        As[(c + 48) * 132 + row] = v3;
    }
    #pragma unroll
    for (int i2 = 0; i2 < 4; ++i2) {
        int j = g + 16 * i2;
        float4 wv = *(const float4*)(W2 + j * 64 + 4 * c);
        *(float4*)(Bs + j * 64 + 4 * c) = wv;
    }
    __syncthreads();
    #pragma unroll 4
    for (int kk = 0; kk < 64; ++kk) {
        float4 a0 = *(const float4*)(As + kk * 132 + 8 * ty);
        float4 a1 = *(const float4*)(As + kk * 132 + 8 * ty + 4);
        float4 bv = *(const float4*)(Bs + kk * 64 + 4 * tx);
        float ar[8] = {a0.x, a0.y, a0.z, a0.w, a1.x, a1.y, a1.z, a1.w};
        float br[4] = {bv.x, bv.y, bv.z, bv.w};
        #pragma unroll
        for (int i = 0; i < 8; ++i)
            #pragma unroll
            for (int j = 0; j < 4; ++j)
                acc[i][j] += ar[i] * br[j];
    }
    float4 bias = *(const float4*)(b2 + 4 * tx);
    #pragma unroll
    for (int i = 0; i < 8; ++i) {
        int grow = block_row + 8 * ty + i;
        if (grow < n) {
            float4 o = make_float4(acc[i][0] + bias.x, acc[i][1] + bias.y,
                                   acc[i][2] + bias.z, acc[i][3] + bias.w);
            *(float4*)(out + (long)grow * 64 + 4 * tx) = o;
        }
    }
}

// ================= fp32 fallback path (small workspace or huge n) =================
__global__ void deg_kernel(const int* __restrict__ dst, float* __restrict__ deg, int E) {
    int e = blockIdx.x * blockDim.x + threadIdx.x;
    if (e < E) atomicAdd(&deg[dst[e]], 1.0f);
}
__global__ void disf_kernel(float* __restrict__ deg, int n) {
    int i = blockIdx.x * blockDim.x + threadIdx.x;
    if (i < n) {
        float d = deg[i];
        deg[i] = (d > 0.0f) ? rsqrtf(d) : 0.0f;
    }
}
__global__ __launch_bounds__(256) void gemm1_f32_kernel(
    const float* __restrict__ x, const float* __restrict__ W1,
    float* __restrict__ z, int n, int nstride)
{
    __shared__ float As[64 * 132];
    __shared__ float Bs[64 * 64];
    __shared__ float sums[128];
    const int t  = threadIdx.x;
    const int tx = t & 15;
    const int ty = t >> 4;
    const int c  = t & 15;
    const int g  = t >> 4;
    const int block_row = blockIdx.x * 128;
    float acc[8][4];
    #pragma unroll
    for (int i = 0; i < 8; ++i)
        #pragma unroll
        for (int j = 0; j < 4; ++j) acc[i][j] = 0.f;
    for (int kp = 0; kp < 2; ++kp) {
        #pragma unroll
        for (int i = 0; i < 8; ++i) {
            int row  = g + 16 * i;
            int grow = block_row + row;
            float v0 = 0.f, v1 = 0.f, v2 = 0.f, v3 = 0.f;
            if (grow < n) {
                const float* xp = x + (long)grow * 128 + kp * 64 + c;
                v0 = xp[0]; v1 = xp[16]; v2 = xp[32]; v3 = xp[48];
            }
            As[(c +  0) * 132 + row] = v0;
            As[(c + 16) * 132 + row] = v1;
            As[(c + 32) * 132 + row] = v2;
            As[(c + 48) * 132 + row] = v3;
            float red = (v0 + v1) + (v2 + v3);
            #pragma unroll
            for (int off = 8; off > 0; off >>= 1) red += __shfl_down(red, off, 16);
            if (c == 0) { if (kp == 0) sums[row] = red; else sums[row] += red; }
        }
        #pragma unroll
        for (int i2 = 0; i2 < 4; ++i2) {
            int kk = g + 16 * i2;
            int kglob = kp * 64 + kk;
            float4 wv = *(const float4*)(W1 + (c >> 2) * 2048 + kglob * 16 + 4 * (c & 3));
            *(float4*)(Bs + kk * 64 + 4 * c) = wv;
        }
        __syncthreads();
        #pragma unroll 4
        for (int kk = 0; kk < 64; ++kk) {
            float4 a0 = *(const float4*)(As + kk * 132 + 8 * ty);
            float4 a1 = *(const float4*)(As + kk * 132 + 8 * ty + 4);
            float4 bv = *(const float4*)(Bs + kk * 64 + 4 * tx);
            float ar[8] = {a0.x, a0.y, a0.z, a0.w, a1.x, a1.y, a1.z, a1.w};
            float br[4] = {bv.x, bv.y, bv.z, bv.w};
            #pragma unroll
            for (int i = 0; i < 8; ++i)
                #pragma unroll
                for (int j = 0; j < 4; ++j)
                    acc[i][j] += ar[i] * br[j];
        }
        __syncthreads();
    }
    int plane = tx >> 2;
    int oo4   = 4 * (tx & 3);
    #pragma unroll
    for (int i = 0; i < 8; ++i) {
        int row  = 8 * ty + i;
        int grow = block_row + row;
        if (grow < n) {
            float s = 1.0f / fmaxf(sums[row], 1e-8f);
            float4 o = make_float4(acc[i][0] * s, acc[i][1] * s, acc[i][2] * s, acc[i][3] * s);
            *(float4*)(z + (long)plane * nstride + (long)grow * 16 + oo4) = o;
        }
    }
}
__global__ __launch_bounds__(256) void spmm_atomic_kernel(
    const float* __restrict__ in, float* __restrict__ out,
    const int* __restrict__ src, const int* __restrict__ dst,
    const float* __restrict__ dis, int E)
{
    int t = blockIdx.x * blockDim.x + threadIdx.x;
    int e = t >> 4, f = t & 15;
    if (e < E) {
        int s = src[e], d = dst[e];
        atomicAdd(&out[d * 16 + f], dis[s] * dis[d] * in[s * 16 + f]);
    }
}
__global__ void bias_relu_kernel(float* __restrict__ z0, const float* __restrict__ b, int total) {
    int i = blockIdx.x * blockDim.x + threadIdx.x;
    if (i < total) {
        float v = z0[i] + b[i & 15];
        z0[i] = v > 0.0f ? v : 0.0f;
    }
}
__global__ __launch_bounds__(256) void gemm2_f32_kernel(
    const float* __restrict__ z, const float* __restrict__ W2,
    const float* __restrict__ b2, float* __restrict__ out, int n, int nstride)
{
    __shared__ float As[64 * 132];
    __shared__ float Bs[64 * 64];
    const int t  = threadIdx.x;
    const int tx = t & 15;
    const int ty = t >> 4;
    const int c  = t & 15;
    const int g  = t >> 4;
    const int block_row = blockIdx.x * 128;
    float acc[8][4];
    #pragma unroll
    for (int i = 0; i < 8; ++i)
        #pragma unroll
        for (int j = 0; j < 4; ++j) acc[i][j] = 0.f;
    #pragma unroll
    for (int i = 0; i < 8; ++i) {
        int row  = g + 16 * i;
        int grow = block_row + row;
        float v0 = 0.f, v1 = 0.f, v2 = 0.f, v3 = 0.f;
        if (grow < n) {
            const float* zp = z + (long)grow * 16 + c;
            v0 = zp[0];
            v1 = zp[(long)nstride];
            v2 = zp[2 * (long)nstride];
            v3 = zp[3 * (long)nstride];
        }
        As[(c +  0) * 132 + row] = v0;
        As[(c + 16) * 132 + row] = v1;
        As[(c + 32) * 132 + row] = v2;
        As[(c + 48) * 132 + row] = v3;
    }
    #pragma unroll
    for (int i2 = 0; i2 < 4; ++i2) {
        int j = g + 16 * i2;
        float4 wv = *(const float4*)(W2 + j * 64 + 4 * c);
        *(float4*)(Bs + j * 64 + 4 * c) = wv;
    }
    __syncthreads();
    #pragma unroll 4
    for (int kk = 0; kk < 64; ++kk) {
        float4 a0 = *(const float4*)(As + kk * 132 + 8 * ty);
        float4 a1 = *(const float4*)(As + kk * 132 + 8 * ty + 4);
        float4 bv = *(const float4*)(Bs + kk * 64 + 4 * tx);
        float ar[8] = {a0.x, a0.y, a0.z, a0.w, a1.x, a1.y, a1.z, a1.w};
        float br[4] = {bv.x, bv.y, bv.z, bv.w};
        #pragma unroll
        for (int i = 0; i < 8; ++i)
            #pragma unroll
            for (int j = 0; j < 4; ++j)
                acc[i][j] += ar[i] * br[j];
    }
    float4 bias = *(const float4*)(b2 + 4 * tx);
    #pragma unroll
    for (int i = 0; i < 8; ++i) {
        int grow = block_row + 8 * ty + i;
        if (grow < n) {
            float4 o = make_float4(acc[i][0] + bias.x, acc[i][1] + bias.y,
                                   acc[i][2] + bias.z, acc[i][3] + bias.w);
            *(float4*)(out + (long)grow * 64 + 4 * tx) = o;
        }
    }
}

static inline size_t align16(size_t v) { return (v + 15) & ~(size_t)15; }

extern "C" void kernel_launch(void* const* d_in, const int* in_sizes, int n_in,
                              void* d_out, int out_size, void* d_ws, size_t ws_size,
                              hipStream_t stream) {
    const float* x   = (const float*)d_in[0];
    const int*   ei  = (const int*)d_in[1];
    const float* W1  = (const float*)d_in[2];
    const float* b1  = (const float*)d_in[3];
    const float* W2  = (const float*)d_in[4];
    const float* bb2 = (const float*)d_in[5];
    float* out = (float*)d_out;

    const int n  = in_sizes[0] / 128;   // 50000
    const int E  = in_sizes[1] / 2;     // 800000
    const int NS = n * 16;

    const int* srcp = ei;
    const int* dstp = ei + E;

    const int nbuck = (n + BKT_SIZE - 1) >> BKT_SHIFT;         // 391
    const int nbA   = (E + CHUNK - 1) / CHUNK;                 // 391
    const int m     = nbuck * nbA;                             // ~153k
    const int nbS   = (m + 255) / 256;                         // scan blocks

    char* wsb = (char*)d_ws;
    // bytes: hist[m] | hofs[m+1] | bsum[1024] | rowptr[n+1] | dis[n] | zb[4*NS u16] | bucketed[E i2] | ecolw[E f2]
    int*   hist   = (int*)wsb;
    int*   hofs   = (int*)(wsb + (size_t)4 * m);
    int*   bsum   = (int*)(wsb + (size_t)4 * (2 * m + 1));
    int*   rowptr = (int*)(wsb + (size_t)4 * (2 * m + 1 + 1024));
    float* dis    = (float*)(wsb + (size_t)4 * (2 * m + 1 + 1024 + n + 1));
    size_t zoffb  = align16((size_t)4 * (2 * m + 1 + 1024 + 2 * n + 1));
    u16*   zb     = (u16*)(wsb + zoffb);
    size_t bkoff  = align16(zoffb + (size_t)2 * 4 * NS);
    int2*  bucketed = (int2*)(wsb + bkoff);
    size_t ecooff = align16(bkoff + (size_t)8 * E);
    float2* ecolw = (float2*)(wsb + ecooff);
    size_t need   = ecooff + (size_t)8 * E;

    int gemm_blocks = (n + 127) / 128;

    if (ws_size >= need && nbuck <= 512 && nbS <= 1024) {
        // ---------- LDS-bucket CSR build (zero global atomics) ----------
        hist_kernel<<<nbA, 256, 0, stream>>>(dstp, hist, E, nbA, nbuck);
        scanA_kernel<<<nbS, 256, 0, stream>>>(hist, hofs, bsum, m);
        scanB_kernel<<<1, 1024, 0, stream>>>(bsum, nbS);
        scanC_kernel<<<nbS, 256, 0, stream>>>(hofs, bsum, m);
        bucket_scatter_kernel<<<nbA, 256, 0, stream>>>(srcp, dstp, hofs, bucketed, E, nbA, nbuck);
        csr_finalize_kernel<<<nbuck, 256, 0, stream>>>(bucketed, hofs, rowptr, dis, ecolw, E, nbA, nbuck, n);
        weight_kernel<<<(E + 255) / 256, 256, 0, stream>>>(ecolw, dis, E);

        gemm1_bf_kernel<<<gemm_blocks, 256, 0, stream>>>(x, W1, zb, n, NS);

        int sb = (8 * n + 255) / 256;
        // layer-1 Horner
        spmm_csr_bf_kernel<<<sb, 256, 0, stream>>>(zb + 3 * NS, zb + 2 * NS, zb + 2 * NS, rowptr, ecolw, nullptr, 0, n);
        spmm_csr_bf_kernel<<<sb, 256, 0, stream>>>(zb + 2 * NS, zb + 1 * NS, zb + 1 * NS, rowptr, ecolw, nullptr, 0, n);
        spmm_csr_bf_kernel<<<sb, 256, 0, stream>>>(zb + 1 * NS, zb,          zb,          rowptr, ecolw, b1,      1, n);
        // layer-2 hops
        spmm_csr_bf_kernel<<<sb, 256, 0, stream>>>(zb,          nullptr, zb + 1 * NS, rowptr, ecolw, nullptr, 0, n);
        spmm_csr_bf_kernel<<<sb, 256, 0, stream>>>(zb + 1 * NS, nullptr, zb + 2 * NS, rowptr, ecolw, nullptr, 0, n);
        spmm_csr_bf_kernel<<<sb, 256, 0, stream>>>(zb + 2 * NS, nullptr, zb + 3 * NS, rowptr, ecolw, nullptr, 0, n);

        gemm2_bf_kernel<<<gemm_blocks, 256, 0, stream>>>(zb, W2, bb2, out, n, NS);
    } else {
        // ---------- fp32 atomic fallback ----------
        float* ws = (float*)d_ws;
        float* dis2 = ws;
        size_t z2off = ((size_t)n + 3) & ~(size_t)3;
        float* z2 = ws + z2off;
        hipMemsetAsync(dis2, 0, n * sizeof(float), stream);
        deg_kernel<<<(E + 255) / 256, 256, 0, stream>>>(dstp, dis2, E);
        disf_kernel<<<(n + 255) / 256, 256, 0, stream>>>(dis2, n);
        gemm1_f32_kernel<<<gemm_blocks, 256, 0, stream>>>(x, W1, z2, n, NS);
        int sb = (16 * E + 255) / 256;
        spmm_atomic_kernel<<<sb, 256, 0, stream>>>(z2 + 3 * NS, z2 + 2 * NS, srcp, dstp, dis2, E);
        spmm_atomic_kernel<<<sb, 256, 0, stream>>>(z2 + 2 * NS, z2 + 1 * NS, srcp, dstp, dis2, E);
        spmm_atomic_kernel<<<sb, 256, 0, stream>>>(z2 + 1 * NS, z2,          srcp, dstp, dis2, E);
        bias_relu_kernel<<<(NS + 255) / 256, 256, 0, stream>>>(z2, b1, NS);
        hipMemsetAsync(z2 + NS, 0, (size_t)3 * NS * sizeof(float), stream);
        spmm_atomic_kernel<<<sb, 256, 0, stream>>>(z2,          z2 + NS,     srcp, dstp, dis2, E);
        spmm_atomic_kernel<<<sb, 256, 0, stream>>>(z2 + NS,     z2 + 2 * NS, srcp, dstp, dis2, E);
        spmm_atomic_kernel<<<sb, 256, 0, stream>>>(z2 + 2 * NS, z2 + 3 * NS, srcp, dstp, dis2, E);
        gemm2_f32_kernel<<<gemm_blocks, 256, 0, stream>>>(z2, W2, bb2, out, n, NS);
    }
}

// Round 13
// 206.165 us; speedup vs baseline: 3.2606x; 1.0445x over previous
//
#include <hip/hip_runtime.h>
#include <hip/hip_bf16.h>

typedef unsigned short u16;
typedef unsigned int u32;

__device__ __forceinline__ float bf2f(u16 h) {
    return __uint_as_float(((u32)h) << 16);
}
__device__ __forceinline__ u16 f2bf(float f) {
    __hip_bfloat16 h = __float2bfloat16(f);   // RNE
    return *reinterpret_cast<u16*>(&h);
}

#define BKT_SHIFT 7
#define BKT_SIZE  128
#define CHUNK     2048   // edges per hist/scatter block

// ---- A1: per-chunk LDS histogram over buckets (dst>>7). No global atomics. ----
__global__ __launch_bounds__(256) void hist_kernel(const int* __restrict__ dst,
                                                   int* __restrict__ hist,
                                                   int E, int nbA, int nbuck) {
    __shared__ int lh[512];
    for (int j = threadIdx.x; j < nbuck; j += 256) lh[j] = 0;
    __syncthreads();
    int base = blockIdx.x * CHUNK;
    int end  = min(E, base + CHUNK);
    for (int e = base + threadIdx.x; e < end; e += 256)
        atomicAdd(&lh[dst[e] >> BKT_SHIFT], 1);
    __syncthreads();
    for (int j = threadIdx.x; j < nbuck; j += 256)
        hist[j * nbA + blockIdx.x] = lh[j];       // bin-major for the scan
}

// ---- hierarchical scan (generic, int) ----
__global__ __launch_bounds__(256) void scanA_kernel(const int* __restrict__ in,
                                                    int* __restrict__ outp1,
                                                    int* __restrict__ bsum, int n) {
    __shared__ int lds[256];
    int i = blockIdx.x * 256 + threadIdx.x;
    int v = (i < n) ? in[i] : 0;
    lds[threadIdx.x] = v;
    __syncthreads();
    #pragma unroll
    for (int off = 1; off < 256; off <<= 1) {
        int t = (threadIdx.x >= off) ? lds[threadIdx.x - off] : 0;
        __syncthreads();
        lds[threadIdx.x] += t;
        __syncthreads();
    }
    if (i < n) outp1[i + 1] = lds[threadIdx.x];
    if (threadIdx.x == 255) bsum[blockIdx.x] = lds[255];
}
__global__ __launch_bounds__(1024) void scanB_kernel(int* __restrict__ bsum, int nb) {
    __shared__ int lds[1024];
    int t = threadIdx.x;
    int v = (t < nb) ? bsum[t] : 0;
    lds[t] = v;
    __syncthreads();
    #pragma unroll
    for (int off = 1; off < 1024; off <<= 1) {
        int u = (t >= off) ? lds[t - off] : 0;
        __syncthreads();
        lds[t] += u;
        __syncthreads();
    }
    if (t < nb) bsum[t] = lds[t] - v;
}
__global__ __launch_bounds__(256) void scanC_kernel(int* __restrict__ outp1,
                                                    const int* __restrict__ bsum, int n) {
    int i = blockIdx.x * 256 + threadIdx.x;
    if (i < n) outp1[i + 1] += bsum[blockIdx.x];
    if (i == 0) outp1[0] = 0;
}

// ---- A3: scatter edges into bucket-grouped array (LDS-atomic local ranks) ----
__global__ __launch_bounds__(256) void bucket_scatter_kernel(
    const int* __restrict__ src, const int* __restrict__ dst,
    const int* __restrict__ hofs, int2* __restrict__ bucketed,
    int E, int nbA, int nbuck)
{
    __shared__ int lbase[512];
    __shared__ int lcnt[512];
    for (int j = threadIdx.x; j < nbuck; j += 256) {
        lbase[j] = hofs[j * nbA + blockIdx.x];
        lcnt[j] = 0;
    }
    __syncthreads();
    int base = blockIdx.x * CHUNK;
    int end  = min(E, base + CHUNK);
    for (int e = base + threadIdx.x; e < end; e += 256) {
        int d = dst[e];
        int b = d >> BKT_SHIFT;
        int r = atomicAdd(&lcnt[b], 1);
        bucketed[lbase[b] + r] = make_int2(src[e], d);
    }
}

// ---- B: one block per bucket -> rowptr, dis, ecol (src only; no weights) ----
__global__ __launch_bounds__(256) void csr_finalize_kernel(
    const int2* __restrict__ bucketed, const int* __restrict__ hofs,
    int* __restrict__ rowptr, float* __restrict__ dis,
    u32* __restrict__ ecol, int E, int nbA, int nbuck, int n)
{
    __shared__ int cnt[BKT_SIZE];
    __shared__ int run[BKT_SIZE];
    int b = blockIdx.x;
    int bstart = hofs[b * nbA];
    int bend   = (b == nbuck - 1) ? E : hofs[(b + 1) * nbA];
    for (int j = threadIdx.x; j < BKT_SIZE; j += 256) cnt[j] = 0;
    __syncthreads();
    for (int i = bstart + threadIdx.x; i < bend; i += 256)
        atomicAdd(&cnt[bucketed[i].y & (BKT_SIZE - 1)], 1);
    __syncthreads();
    if (threadIdx.x == 0) {
        int runacc = 0;
        for (int j = 0; j < BKT_SIZE; ++j) {
            int c = cnt[j];
            run[j] = runacc;
            runacc += c;
        }
    }
    __syncthreads();
    for (int j = threadIdx.x; j < BKT_SIZE; j += 256) {
        int d = b * BKT_SIZE + j;
        if (d < n) {
            rowptr[d] = bstart + run[j];
            int c = cnt[j];
            dis[d] = (c > 0) ? rsqrtf((float)c) : 0.0f;
        }
    }
    if (b == 0 && threadIdx.x == 0) rowptr[n] = E;
    __syncthreads();
    for (int i = bstart + threadIdx.x; i < bend; i += 256) {
        int2 p = bucketed[i];
        int j = p.y & (BKT_SIZE - 1);
        int r = atomicAdd(&run[j], 1);
        ecol[bstart + r] = (u32)p.x;
    }
}

// ---- GEMM1 (tiled): P0 = z0 (normal), P1..P3 = dis .* z_k (tilde space) ----
__global__ __launch_bounds__(256) void gemm1_bf_kernel(
    const float* __restrict__ x, const float* __restrict__ W1,
    const float* __restrict__ dis, u16* __restrict__ zb, int n, int nstride)
{
    __shared__ float As[64 * 132];
    __shared__ float Bs[64 * 64];
    __shared__ float sums[128];
    const int t  = threadIdx.x;
    const int tx = t & 15;
    const int ty = t >> 4;
    const int c  = t & 15;
    const int g  = t >> 4;
    const int block_row = blockIdx.x * 128;

    float acc[8][4];
    #pragma unroll
    for (int i = 0; i < 8; ++i)
        #pragma unroll
        for (int j = 0; j < 4; ++j) acc[i][j] = 0.f;

    for (int kp = 0; kp < 2; ++kp) {
        #pragma unroll
        for (int i = 0; i < 8; ++i) {
            int row  = g + 16 * i;
            int grow = block_row + row;
            float v0 = 0.f, v1 = 0.f, v2 = 0.f, v3 = 0.f;
            if (grow < n) {
                const float* xp = x + (long)grow * 128 + kp * 64 + c;
                v0 = xp[0]; v1 = xp[16]; v2 = xp[32]; v3 = xp[48];
            }
            As[(c +  0) * 132 + row] = v0;
            As[(c + 16) * 132 + row] = v1;
            As[(c + 32) * 132 + row] = v2;
            As[(c + 48) * 132 + row] = v3;
            float red = (v0 + v1) + (v2 + v3);
            #pragma unroll
            for (int off = 8; off > 0; off >>= 1) red += __shfl_down(red, off, 16);
            if (c == 0) { if (kp == 0) sums[row] = red; else sums[row] += red; }
        }
        #pragma unroll
        for (int i2 = 0; i2 < 4; ++i2) {
            int kk = g + 16 * i2;
            int kglob = kp * 64 + kk;
            float4 wv = *(const float4*)(W1 + (c >> 2) * 2048 + kglob * 16 + 4 * (c & 3));
            *(float4*)(Bs + kk * 64 + 4 * c) = wv;
        }
        __syncthreads();
        #pragma unroll 4
        for (int kk = 0; kk < 64; ++kk) {
            float4 a0 = *(const float4*)(As + kk * 132 + 8 * ty);
            float4 a1 = *(const float4*)(As + kk * 132 + 8 * ty + 4);
            float4 bv = *(const float4*)(Bs + kk * 64 + 4 * tx);
            float ar[8] = {a0.x, a0.y, a0.z, a0.w, a1.x, a1.y, a1.z, a1.w};
            float br[4] = {bv.x, bv.y, bv.z, bv.w};
            #pragma unroll
            for (int i = 0; i < 8; ++i)
                #pragma unroll
                for (int j = 0; j < 4; ++j)
                    acc[i][j] += ar[i] * br[j];
        }
        __syncthreads();
    }
    int plane = tx >> 2;
    int oo4   = 4 * (tx & 3);
    #pragma unroll
    for (int i = 0; i < 8; ++i) {
        int row  = 8 * ty + i;
        int grow = block_row + row;
        if (grow < n) {
            float s = 1.0f / fmaxf(sums[row], 1e-8f);
            if (plane != 0) s *= dis[grow];          // tilde space for SpMM inputs
            ushort4 o;
            o.x = f2bf(acc[i][0] * s); o.y = f2bf(acc[i][1] * s);
            o.z = f2bf(acc[i][2] * s); o.w = f2bf(acc[i][3] * s);
            *(ushort4*)(zb + (long)plane * nstride + (long)grow * 16 + oo4) = o;
        }
    }
}

// ---- CSR SpMM, tilde form: unweighted gather-sum, per-row scale in epilogue ----
// out1[r] = relu?( scale1 * S + addsrc[r] + b ), scale1 = sq1 ? dis^2 : dis
// out2[r] = dis[r] * out1val (pre-rounding), if out2 != null
__global__ __launch_bounds__(256) void spmm_csr_bf_kernel(
    const u16* __restrict__ in, const u16* __restrict__ addsrc,
    u16* __restrict__ out1, u16* __restrict__ out2,
    const int* __restrict__ rowptr, const u32* __restrict__ ecol,
    const float* __restrict__ dis, const float* __restrict__ b,
    int relu, int sq1, int n)
{
    int t = blockIdx.x * blockDim.x + threadIdx.x;
    int r = t >> 3, q = t & 7;
    if (r >= n) return;
    int e0 = rowptr[r], e1 = rowptr[r + 1];
    float ax0=0,ay0=0, ax1=0,ay1=0, ax2=0,ay2=0, ax3=0,ay3=0;
    int e = e0;
    for (; e + 4 <= e1; e += 4) {
        u32 s0 = ecol[e], s1 = ecol[e+1], s2 = ecol[e+2], s3 = ecol[e+3];
        ushort2 v0 = *((const ushort2*)(in + (size_t)s0 * 16) + q);
        ushort2 v1 = *((const ushort2*)(in + (size_t)s1 * 16) + q);
        ushort2 v2 = *((const ushort2*)(in + (size_t)s2 * 16) + q);
        ushort2 v3 = *((const ushort2*)(in + (size_t)s3 * 16) + q);
        ax0 += bf2f(v0.x); ay0 += bf2f(v0.y);
        ax1 += bf2f(v1.x); ay1 += bf2f(v1.y);
        ax2 += bf2f(v2.x); ay2 += bf2f(v2.y);
        ax3 += bf2f(v3.x); ay3 += bf2f(v3.y);
    }
    for (; e < e1; ++e) {
        ushort2 v0 = *((const ushort2*)(in + (size_t)ecol[e] * 16) + q);
        ax0 += bf2f(v0.x); ay0 += bf2f(v0.y);
    }
    float Sx = (ax0 + ax1) + (ax2 + ax3);
    float Sy = (ay0 + ay1) + (ay2 + ay3);
    float d1 = dis[r];
    float sc1 = sq1 ? d1 * d1 : d1;
    float Ax = Sx * sc1, Ay = Sy * sc1;
    if (addsrc) {
        ushort2 s = *((const ushort2*)(addsrc + (size_t)r * 16) + q);
        Ax += bf2f(s.x); Ay += bf2f(s.y);
    }
    if (b) {
        Ax += b[2 * q];
        Ay += b[2 * q + 1];
    }
    if (relu) {
        Ax = fmaxf(Ax, 0.f);
        Ay = fmaxf(Ay, 0.f);
    }
    ushort2 o; o.x = f2bf(Ax); o.y = f2bf(Ay);
    *((ushort2*)(out1 + (size_t)r * 16) + q) = o;
    if (out2) {
        ushort2 o2; o2.x = f2bf(Ax * d1); o2.y = f2bf(Ay * d1);
        *((ushort2*)(out2 + (size_t)r * 16) + q) = o2;
    }
}

// ---- GEMM2 (tiled, bf16 planes in, fp32 out): out = cat(P0..P3) @ W2cat + b2 ----
__global__ __launch_bounds__(256) void gemm2_bf_kernel(
    const u16* __restrict__ zb, const float* __restrict__ W2,
    const float* __restrict__ b2, float* __restrict__ out, int n, int nstride)
{
    __shared__ float As[64 * 132];
    __shared__ float Bs[64 * 64];
    const int t  = threadIdx.x;
    const int tx = t & 15;
    const int ty = t >> 4;
    const int c  = t & 15;
    const int g  = t >> 4;
    const int block_row = blockIdx.x * 128;

    float acc[8][4];
    #pragma unroll
    for (int i = 0; i < 8; ++i)
        #pragma unroll
        for (int j = 0; j < 4; ++j) acc[i][j] = 0.f;

    #pragma unroll
    for (int i = 0; i < 8; ++i) {
        int row  = g + 16 * i;
        int grow = block_row + row;
        float v0 = 0.f, v1 = 0.f, v2 = 0.f, v3 = 0.f;
        if (grow < n) {
            const u16* zp = zb + (long)grow * 16 + c;
            v0 = bf2f(zp[0]);
            v1 = bf2f(zp[(long)nstride]);
            v2 = bf2f(zp[2 * (long)nstride]);
            v3 = bf2f(zp[3 * (long)nstride]);
        }
        As[(c +  0) * 132 + row] = v0;
        As[(c + 16) * 132 + row] = v1;
        As[(c + 32) * 132 + row] = v2;
        As[(c + 48) * 132 + row] = v3;
    }
    #pragma unroll
    for (int i2 = 0; i2 < 4; ++i2) {
        int j = g + 16 * i2;
        float4 wv = *(const float4*)(W2 + j * 64 + 4 * c);
        *(float4*)(Bs + j * 64 + 4 * c) = wv;
    }
    __syncthreads();
    #pragma unroll 4
    for (int kk = 0; kk < 64; ++kk) {
        float4 a0 = *(const float4*)(As + kk * 132 + 8 * ty);
        float4 a1 = *(const float4*)(As + kk * 132 + 8 * ty + 4);
        float4 bv = *(const float4*)(Bs + kk * 64 + 4 * tx);
        float ar[8] = {a0.x, a0.y, a0.z, a0.w, a1.x, a1.y, a1.z, a1.w};
        float br[4] = {bv.x, bv.y, bv.z, bv.w};
        #pragma unroll
        for (int i = 0; i < 8; ++i)
            #pragma unroll
            for (int j = 0; j < 4; ++j)
                acc[i][j] += ar[i] * br[j];
    }
    float4 bias = *(const float4*)(b2 + 4 * tx);
    #pragma unroll
    for (int i = 0; i < 8; ++i) {
        int grow = block_row + 8 * ty + i;
        if (grow < n) {
            float4 o = make_float4(acc[i][0] + bias.x, acc[i][1] + bias.y,
                                   acc[i][2] + bias.z, acc[i][3] + bias.w);
            *(float4*)(out + (long)grow * 64 + 4 * tx) = o;
        }
    }
}

// ================= fp32 fallback path (small workspace or huge n) =================
__global__ void deg_kernel(const int* __restrict__ dst, float* __restrict__ deg, int E) {
    int e = blockIdx.x * blockDim.x + threadIdx.x;
    if (e < E) atomicAdd(&deg[dst[e]], 1.0f);
}
__global__ void disf_kernel(float* __restrict__ deg, int n) {
    int i = blockIdx.x * blockDim.x + threadIdx.x;
    if (i < n) {
        float d = deg[i];
        deg[i] = (d > 0.0f) ? rsqrtf(d) : 0.0f;
    }
}
__global__ __launch_bounds__(256) void gemm1_f32_kernel(
    const float* __restrict__ x, const float* __restrict__ W1,
    float* __restrict__ z, int n, int nstride)
{
    __shared__ float As[64 * 132];
    __shared__ float Bs[64 * 64];
    __shared__ float sums[128];
    const int t  = threadIdx.x;
    const int tx = t & 15;
    const int ty = t >> 4;
    const int c  = t & 15;
    const int g  = t >> 4;
    const int block_row = blockIdx.x * 128;
    float acc[8][4];
    #pragma unroll
    for (int i = 0; i < 8; ++i)
        #pragma unroll
        for (int j = 0; j < 4; ++j) acc[i][j] = 0.f;
    for (int kp = 0; kp < 2; ++kp) {
        #pragma unroll
        for (int i = 0; i < 8; ++i) {
            int row  = g + 16 * i;
            int grow = block_row + row;
            float v0 = 0.f, v1 = 0.f, v2 = 0.f, v3 = 0.f;
            if (grow < n) {
                const float* xp = x + (long)grow * 128 + kp * 64 + c;
                v0 = xp[0]; v1 = xp[16]; v2 = xp[32]; v3 = xp[48];
            }
            As[(c +  0) * 132 + row] = v0;
            As[(c + 16) * 132 + row] = v1;
            As[(c + 32) * 132 + row] = v2;
            As[(c + 48) * 132 + row] = v3;
            float red = (v0 + v1) + (v2 + v3);
            #pragma unroll
            for (int off = 8; off > 0; off >>= 1) red += __shfl_down(red, off, 16);
            if (c == 0) { if (kp == 0) sums[row] = red; else sums[row] += red; }
        }
        #pragma unroll
        for (int i2 = 0; i2 < 4; ++i2) {
            int kk = g + 16 * i2;
            int kglob = kp * 64 + kk;
            float4 wv = *(const float4*)(W1 + (c >> 2) * 2048 + kglob * 16 + 4 * (c & 3));
            *(float4*)(Bs + kk * 64 + 4 * c) = wv;
        }
        __syncthreads();
        #pragma unroll 4
        for (int kk = 0; kk < 64; ++kk) {
            float4 a0 = *(const float4*)(As + kk * 132 + 8 * ty);
            float4 a1 = *(const float4*)(As + kk * 132 + 8 * ty + 4);
            float4 bv = *(const float4*)(Bs + kk * 64 + 4 * tx);
            float ar[8] = {a0.x, a0.y, a0.z, a0.w, a1.x, a1.y, a1.z, a1.w};
            float br[4] = {bv.x, bv.y, bv.z, bv.w};
            #pragma unroll
            for (int i = 0; i < 8; ++i)
                #pragma unroll
                for (int j = 0; j < 4; ++j)
                    acc[i][j] += ar[i] * br[j];
        }
        __syncthreads();
    }
    int plane = tx >> 2;
    int oo4   = 4 * (tx & 3);
    #pragma unroll
    for (int i = 0; i < 8; ++i) {
        int row  = 8 * ty + i;
        int grow = block_row + row;
        if (grow < n) {
            float s = 1.0f / fmaxf(sums[row], 1e-8f);
            float4 o = make_float4(acc[i][0] * s, acc[i][1] * s, acc[i][2] * s, acc[i][3] * s);
            *(float4*)(z + (long)plane * nstride + (long)grow * 16 + oo4) = o;
        }
    }
}
__global__ __launch_bounds__(256) void spmm_atomic_kernel(
    const float* __restrict__ in, float* __restrict__ out,
    const int* __restrict__ src, const int* __restrict__ dst,
    const float* __restrict__ dis, int E)
{
    int t = blockIdx.x * blockDim.x + threadIdx.x;
    int e = t >> 4, f = t & 15;
    if (e < E) {
        int s = src[e], d = dst[e];
        atomicAdd(&out[d * 16 + f], dis[s] * dis[d] * in[s * 16 + f]);
    }
}
__global__ void bias_relu_kernel(float* __restrict__ z0, const float* __restrict__ b, int total) {
    int i = blockIdx.x * blockDim.x + threadIdx.x;
    if (i < total) {
        float v = z0[i] + b[i & 15];
        z0[i] = v > 0.0f ? v : 0.0f;
    }
}
__global__ __launch_bounds__(256) void gemm2_f32_kernel(
    const float* __restrict__ z, const float* __restrict__ W2,
    const float* __restrict__ b2, float* __restrict__ out, int n, int nstride)
{
    __shared__ float As[64 * 132];
    __shared__ float Bs[64 * 64];
    const int t  = threadIdx.x;
    const int tx = t & 15;
    const int ty = t >> 4;
    const int c  = t & 15;
    const int g  = t >> 4;
    const int block_row = blockIdx.x * 128;
    float acc[8][4];
    #pragma unroll
    for (int i = 0; i < 8; ++i)
        #pragma unroll
        for (int j = 0; j < 4; ++j) acc[i][j] = 0.f;
    #pragma unroll
    for (int i = 0; i < 8; ++i) {
        int row  = g + 16 * i;
        int grow = block_row + row;
        float v0 = 0.f, v1 = 0.f, v2 = 0.f, v3 = 0.f;
        if (grow < n) {
            const float* zp = z + (long)grow * 16 + c;
            v0 = zp[0];
            v1 = zp[(long)nstride];
            v2 = zp[2 * (long)nstride];
            v3 = zp[3 * (long)nstride];
        }
        As[(c +  0) * 132 + row] = v0;
        As[(c + 16) * 132 + row] = v1;
        As[(c + 32) * 132 + row] = v2;
        As[(c + 48) * 132 + row] = v3;
    }
    #pragma unroll
    for (int i2 = 0; i2 < 4; ++i2) {
        int j = g + 16 * i2;
        float4 wv = *(const float4*)(W2 + j * 64 + 4 * c);
        *(float4*)(Bs + j * 64 + 4 * c) = wv;
    }
    __syncthreads();
    #pragma unroll 4
    for (int kk = 0; kk < 64; ++kk) {
        float4 a0 = *(const float4*)(As + kk * 132 + 8 * ty);
        float4 a1 = *(const float4*)(As + kk * 132 + 8 * ty + 4);
        float4 bv = *(const float4*)(Bs + kk * 64 + 4 * tx);
        float ar[8] = {a0.x, a0.y, a0.z, a0.w, a1.x, a1.y, a1.z, a1.w};
        float br[4] = {bv.x, bv.y, bv.z, bv.w};
        #pragma unroll
        for (int i = 0; i < 8; ++i)
            #pragma unroll
            for (int j = 0; j < 4; ++j)
                acc[i][j] += ar[i] * br[j];
    }
    float4 bias = *(const float4*)(b2 + 4 * tx);
    #pragma unroll
    for (int i = 0; i < 8; ++i) {
        int grow = block_row + 8 * ty + i;
        if (grow < n) {
            float4 o = make_float4(acc[i][0] + bias.x, acc[i][1] + bias.y,
                                   acc[i][2] + bias.z, acc[i][3] + bias.w);
            *(float4*)(out + (long)grow * 64 + 4 * tx) = o;
        }
    }
}

static inline size_t align16(size_t v) { return (v + 15) & ~(size_t)15; }

extern "C" void kernel_launch(void* const* d_in, const int* in_sizes, int n_in,
                              void* d_out, int out_size, void* d_ws, size_t ws_size,
                              hipStream_t stream) {
    const float* x   = (const float*)d_in[0];
    const int*   ei  = (const int*)d_in[1];
    const float* W1  = (const float*)d_in[2];
    const float* b1  = (const float*)d_in[3];
    const float* W2  = (const float*)d_in[4];
    const float* bb2 = (const float*)d_in[5];
    float* out = (float*)d_out;

    const int n  = in_sizes[0] / 128;   // 50000
    const int E  = in_sizes[1] / 2;     // 800000
    const int NS = n * 16;

    const int* srcp = ei;
    const int* dstp = ei + E;

    const int nbuck = (n + BKT_SIZE - 1) >> BKT_SHIFT;
    const int nbA   = (E + CHUNK - 1) / CHUNK;
    const int m     = nbuck * nbA;
    const int nbS   = (m + 255) / 256;

    char* wsb = (char*)d_ws;
    // bytes: hist[m] | hofs[m+1] | bsum[1024] | rowptr[n+1] | dis[n] | zb[6*NS u16] | bucketed[E i2] | ecol[E u32]
    int*   hist   = (int*)wsb;
    int*   hofs   = (int*)(wsb + (size_t)4 * m);
    int*   bsum   = (int*)(wsb + (size_t)4 * (2 * m + 1));
    int*   rowptr = (int*)(wsb + (size_t)4 * (2 * m + 1 + 1024));
    float* dis    = (float*)(wsb + (size_t)4 * (2 * m + 1 + 1024 + n + 1));
    size_t zoffb  = align16((size_t)4 * (2 * m + 1 + 1024 + 2 * n + 1));
    u16*   zb     = (u16*)(wsb + zoffb);
    size_t bkoff  = align16(zoffb + (size_t)2 * 6 * NS);
    int2*  bucketed = (int2*)(wsb + bkoff);
    size_t ecooff = align16(bkoff + (size_t)8 * E);
    u32*   ecol   = (u32*)(wsb + ecooff);
    size_t need   = ecooff + (size_t)4 * E;

    int gemm_blocks = (n + 127) / 128;
    u16 *P0 = zb, *P1 = zb + NS, *P2 = zb + 2 * NS, *P3 = zb + 3 * NS;
    u16 *T0 = zb + 4 * NS, *T1 = zb + 5 * NS;

    if (ws_size >= need && nbuck <= 512 && nbS <= 1024) {
        // ---------- LDS-bucket CSR build (zero global atomics, no weights) ----------
        hist_kernel<<<nbA, 256, 0, stream>>>(dstp, hist, E, nbA, nbuck);
        scanA_kernel<<<nbS, 256, 0, stream>>>(hist, hofs, bsum, m);
        scanB_kernel<<<1, 1024, 0, stream>>>(bsum, nbS);
        scanC_kernel<<<nbS, 256, 0, stream>>>(hofs, bsum, m);
        bucket_scatter_kernel<<<nbA, 256, 0, stream>>>(srcp, dstp, hofs, bucketed, E, nbA, nbuck);
        csr_finalize_kernel<<<nbuck, 256, 0, stream>>>(bucketed, hofs, rowptr, dis, ecol, E, nbA, nbuck, n);

        gemm1_bf_kernel<<<gemm_blocks, 256, 0, stream>>>(x, W1, dis, zb, n, NS);

        int sb = (8 * n + 255) / 256;
        // L1 Horner (tilde space: scale1 = dis^2 = 1/deg)
        spmm_csr_bf_kernel<<<sb, 256, 0, stream>>>(P3, P2, P2, nullptr, rowptr, ecol, dis, nullptr, 0, 1, n);
        spmm_csr_bf_kernel<<<sb, 256, 0, stream>>>(P2, P1, P1, nullptr, rowptr, ecol, dis, nullptr, 0, 1, n);
        // h1 = relu(z0 + dis*S + b1); T0 = dis*h1
        spmm_csr_bf_kernel<<<sb, 256, 0, stream>>>(P1, P0, P0, T0, rowptr, ecol, dis, b1, 1, 0, n);
        // L2 hops: g_k = dis*S (gemm2 input), tilde copy = dis*g_k
        spmm_csr_bf_kernel<<<sb, 256, 0, stream>>>(T0, nullptr, P1, T1, rowptr, ecol, dis, nullptr, 0, 0, n);
        spmm_csr_bf_kernel<<<sb, 256, 0, stream>>>(T1, nullptr, P2, T0, rowptr, ecol, dis, nullptr, 0, 0, n);
        spmm_csr_bf_kernel<<<sb, 256, 0, stream>>>(T0, nullptr, P3, nullptr, rowptr, ecol, dis, nullptr, 0, 0, n);

        gemm2_bf_kernel<<<gemm_blocks, 256, 0, stream>>>(zb, W2, bb2, out, n, NS);
    } else {
        // ---------- fp32 atomic fallback ----------
        float* ws = (float*)d_ws;
        float* dis2 = ws;
        size_t z2off = ((size_t)n + 3) & ~(size_t)3;
        float* z2 = ws + z2off;
        hipMemsetAsync(dis2, 0, n * sizeof(float), stream);
        deg_kernel<<<(E + 255) / 256, 256, 0, stream>>>(dstp, dis2, E);
        disf_kernel<<<(n + 255) / 256, 256, 0, stream>>>(dis2, n);
        gemm1_f32_kernel<<<gemm_blocks, 256, 0, stream>>>(x, W1, z2, n, NS);
        int sb = (16 * E + 255) / 256;
        spmm_atomic_kernel<<<sb, 256, 0, stream>>>(z2 + 3 * NS, z2 + 2 * NS, srcp, dstp, dis2, E);
        spmm_atomic_kernel<<<sb, 256, 0, stream>>>(z2 + 2 * NS, z2 + 1 * NS, srcp, dstp, dis2, E);
        spmm_atomic_kernel<<<sb, 256, 0, stream>>>(z2 + 1 * NS, z2,          srcp, dstp, dis2, E);
        bias_relu_kernel<<<(NS + 255) / 256, 256, 0, stream>>>(z2, b1, NS);
        hipMemsetAsync(z2 + NS, 0, (size_t)3 * NS * sizeof(float), stream);
        spmm_atomic_kernel<<<sb, 256, 0, stream>>>(z2,          z2 + NS,     srcp, dstp, dis2, E);
        spmm_atomic_kernel<<<sb, 256, 0, stream>>>(z2 + NS,     z2 + 2 * NS, srcp, dstp, dis2, E);
        spmm_atomic_kernel<<<sb, 256, 0, stream>>>(z2 + 2 * NS, z2 + 3 * NS, srcp, dstp, dis2, E);
        gemm2_f32_kernel<<<gemm_blocks, 256, 0, stream>>>(z2, W2, bb2, out, n, NS);
    }
}

// Round 14
// 205.061 us; speedup vs baseline: 3.2782x; 1.0054x over previous
//
#include <hip/hip_runtime.h>
#include <hip/hip_bf16.h>

typedef unsigned short u16;
typedef unsigned int u32;

__device__ __forceinline__ float bf2f(u16 h) {
    return __uint_as_float(((u32)h) << 16);
}
__device__ __forceinline__ u16 f2bf(float f) {
    __hip_bfloat16 h = __float2bfloat16(f);   // RNE
    return *reinterpret_cast<u16*>(&h);
}

#define BKT_SHIFT 7
#define BKT_SIZE  128
#define CHUNK     2048   // edges per hist/scatter block
#define SPMM_ROWS 32     // rows per spmm block
#define SPMM_LDSE 2048   // LDS edge capacity (4x Poisson-mean headroom)

// ---- A1: per-chunk LDS histogram over buckets (dst>>7). No global atomics. ----
__global__ __launch_bounds__(256) void hist_kernel(const int* __restrict__ dst,
                                                   int* __restrict__ hist,
                                                   int E, int nbA, int nbuck) {
    __shared__ int lh[512];
    for (int j = threadIdx.x; j < nbuck; j += 256) lh[j] = 0;
    __syncthreads();
    int base = blockIdx.x * CHUNK;
    int end  = min(E, base + CHUNK);
    for (int e = base + threadIdx.x; e < end; e += 256)
        atomicAdd(&lh[dst[e] >> BKT_SHIFT], 1);
    __syncthreads();
    for (int j = threadIdx.x; j < nbuck; j += 256)
        hist[j * nbA + blockIdx.x] = lh[j];       // bin-major for the scan
}

// ---- hierarchical scan (generic, int) ----
__global__ __launch_bounds__(256) void scanA_kernel(const int* __restrict__ in,
                                                    int* __restrict__ outp1,
                                                    int* __restrict__ bsum, int n) {
    __shared__ int lds[256];
    int i = blockIdx.x * 256 + threadIdx.x;
    int v = (i < n) ? in[i] : 0;
    lds[threadIdx.x] = v;
    __syncthreads();
    #pragma unroll
    for (int off = 1; off < 256; off <<= 1) {
        int t = (threadIdx.x >= off) ? lds[threadIdx.x - off] : 0;
        __syncthreads();
        lds[threadIdx.x] += t;
        __syncthreads();
    }
    if (i < n) outp1[i + 1] = lds[threadIdx.x];
    if (threadIdx.x == 255) bsum[blockIdx.x] = lds[255];
}
__global__ __launch_bounds__(1024) void scanB_kernel(int* __restrict__ bsum, int nb) {
    __shared__ int lds[1024];
    int t = threadIdx.x;
    int v = (t < nb) ? bsum[t] : 0;
    lds[t] = v;
    __syncthreads();
    #pragma unroll
    for (int off = 1; off < 1024; off <<= 1) {
        int u = (t >= off) ? lds[t - off] : 0;
        __syncthreads();
        lds[t] += u;
        __syncthreads();
    }
    if (t < nb) bsum[t] = lds[t] - v;
}
__global__ __launch_bounds__(256) void scanC_kernel(int* __restrict__ outp1,
                                                    const int* __restrict__ bsum, int n) {
    int i = blockIdx.x * 256 + threadIdx.x;
    if (i < n) outp1[i + 1] += bsum[blockIdx.x];
    if (i == 0) outp1[0] = 0;
}

// ---- A3: scatter edges into bucket-grouped array (LDS-atomic local ranks) ----
__global__ __launch_bounds__(256) void bucket_scatter_kernel(
    const int* __restrict__ src, const int* __restrict__ dst,
    const int* __restrict__ hofs, int2* __restrict__ bucketed,
    int E, int nbA, int nbuck)
{
    __shared__ int lbase[512];
    __shared__ int lcnt[512];
    for (int j = threadIdx.x; j < nbuck; j += 256) {
        lbase[j] = hofs[j * nbA + blockIdx.x];
        lcnt[j] = 0;
    }
    __syncthreads();
    int base = blockIdx.x * CHUNK;
    int end  = min(E, base + CHUNK);
    for (int e = base + threadIdx.x; e < end; e += 256) {
        int d = dst[e];
        int b = d >> BKT_SHIFT;
        int r = atomicAdd(&lcnt[b], 1);
        bucketed[lbase[b] + r] = make_int2(src[e], d);
    }
}

// ---- B: one block per bucket -> rowptr, dis, ecol (src only; no weights) ----
__global__ __launch_bounds__(256) void csr_finalize_kernel(
    const int2* __restrict__ bucketed, const int* __restrict__ hofs,
    int* __restrict__ rowptr, float* __restrict__ dis,
    u32* __restrict__ ecol, int E, int nbA, int nbuck, int n)
{
    __shared__ int cnt[BKT_SIZE];
    __shared__ int run[BKT_SIZE];
    int b = blockIdx.x;
    int bstart = hofs[b * nbA];
    int bend   = (b == nbuck - 1) ? E : hofs[(b + 1) * nbA];
    for (int j = threadIdx.x; j < BKT_SIZE; j += 256) cnt[j] = 0;
    __syncthreads();
    for (int i = bstart + threadIdx.x; i < bend; i += 256)
        atomicAdd(&cnt[bucketed[i].y & (BKT_SIZE - 1)], 1);
    __syncthreads();
    if (threadIdx.x == 0) {
        int runacc = 0;
        for (int j = 0; j < BKT_SIZE; ++j) {
            int c = cnt[j];
            run[j] = runacc;
            runacc += c;
        }
    }
    __syncthreads();
    for (int j = threadIdx.x; j < BKT_SIZE; j += 256) {
        int d = b * BKT_SIZE + j;
        if (d < n) {
            rowptr[d] = bstart + run[j];
            int c = cnt[j];
            dis[d] = (c > 0) ? rsqrtf((float)c) : 0.0f;
        }
    }
    if (b == 0 && threadIdx.x == 0) rowptr[n] = E;
    __syncthreads();
    for (int i = bstart + threadIdx.x; i < bend; i += 256) {
        int2 p = bucketed[i];
        int j = p.y & (BKT_SIZE - 1);
        int r = atomicAdd(&run[j], 1);
        ecol[bstart + r] = (u32)p.x;
    }
}

// ---- GEMM1 (tiled): P0 = z0 (normal), P1..P3 = dis .* z_k (tilde space) ----
__global__ __launch_bounds__(256) void gemm1_bf_kernel(
    const float* __restrict__ x, const float* __restrict__ W1,
    const float* __restrict__ dis, u16* __restrict__ zb, int n, int nstride)
{
    __shared__ float As[64 * 132];
    __shared__ float Bs[64 * 64];
    __shared__ float sums[128];
    const int t  = threadIdx.x;
    const int tx = t & 15;
    const int ty = t >> 4;
    const int c  = t & 15;
    const int g  = t >> 4;
    const int block_row = blockIdx.x * 128;

    float acc[8][4];
    #pragma unroll
    for (int i = 0; i < 8; ++i)
        #pragma unroll
        for (int j = 0; j < 4; ++j) acc[i][j] = 0.f;

    for (int kp = 0; kp < 2; ++kp) {
        #pragma unroll
        for (int i = 0; i < 8; ++i) {
            int row  = g + 16 * i;
            int grow = block_row + row;
            float v0 = 0.f, v1 = 0.f, v2 = 0.f, v3 = 0.f;
            if (grow < n) {
                const float* xp = x + (long)grow * 128 + kp * 64 + c;
                v0 = xp[0]; v1 = xp[16]; v2 = xp[32]; v3 = xp[48];
            }
            As[(c +  0) * 132 + row] = v0;
            As[(c + 16) * 132 + row] = v1;
            As[(c + 32) * 132 + row] = v2;
            As[(c + 48) * 132 + row] = v3;
            float red = (v0 + v1) + (v2 + v3);
            #pragma unroll
            for (int off = 8; off > 0; off >>= 1) red += __shfl_down(red, off, 16);
            if (c == 0) { if (kp == 0) sums[row] = red; else sums[row] += red; }
        }
        #pragma unroll
        for (int i2 = 0; i2 < 4; ++i2) {
            int kk = g + 16 * i2;
            int kglob = kp * 64 + kk;
            float4 wv = *(const float4*)(W1 + (c >> 2) * 2048 + kglob * 16 + 4 * (c & 3));
            *(float4*)(Bs + kk * 64 + 4 * c) = wv;
        }
        __syncthreads();
        #pragma unroll 4
        for (int kk = 0; kk < 64; ++kk) {
            float4 a0 = *(const float4*)(As + kk * 132 + 8 * ty);
            float4 a1 = *(const float4*)(As + kk * 132 + 8 * ty + 4);
            float4 bv = *(const float4*)(Bs + kk * 64 + 4 * tx);
            float ar[8] = {a0.x, a0.y, a0.z, a0.w, a1.x, a1.y, a1.z, a1.w};
            float br[4] = {bv.x, bv.y, bv.z, bv.w};
            #pragma unroll
            for (int i = 0; i < 8; ++i)
                #pragma unroll
                for (int j = 0; j < 4; ++j)
                    acc[i][j] += ar[i] * br[j];
        }
        __syncthreads();
    }
    int plane = tx >> 2;
    int oo4   = 4 * (tx & 3);
    #pragma unroll
    for (int i = 0; i < 8; ++i) {
        int row  = 8 * ty + i;
        int grow = block_row + row;
        if (grow < n) {
            float s = 1.0f / fmaxf(sums[row], 1e-8f);
            if (plane != 0) s *= dis[grow];          // tilde space for SpMM inputs
            ushort4 o;
            o.x = f2bf(acc[i][0] * s); o.y = f2bf(acc[i][1] * s);
            o.z = f2bf(acc[i][2] * s); o.w = f2bf(acc[i][3] * s);
            *(ushort4*)(zb + (long)plane * nstride + (long)grow * 16 + oo4) = o;
        }
    }
}

// ---- CSR SpMM, tilde form, LDS-staged edge indices ----
// Block owns 32 consecutive rows; their edges are one contiguous CSR range.
// Stage indices coalesced into LDS (kills half of all VMEM transactions:
// the per-row 4B index reads), then 8 lanes/row gather features.
// out1[r] = relu?( scale1 * S + addsrc[r] + b ), scale1 = sq1 ? dis^2 : dis
// out2[r] = dis[r] * out1val (pre-rounding), if out2 != null
__global__ __launch_bounds__(256) void spmm_csr_bf_kernel(
    const u16* __restrict__ in, const u16* __restrict__ addsrc,
    u16* __restrict__ out1, u16* __restrict__ out2,
    const int* __restrict__ rowptr, const u32* __restrict__ ecol,
    const float* __restrict__ dis, const float* __restrict__ b,
    int relu, int sq1, int n)
{
    __shared__ u32 eld[SPMM_LDSE];
    int r0 = blockIdx.x * SPMM_ROWS;
    if (r0 >= n) return;
    int rend = min(n, r0 + SPMM_ROWS);
    int estart = rowptr[r0];
    int eendb  = rowptr[rend];
    int ne = eendb - estart;
    bool lds_ok = (ne <= SPMM_LDSE);
    if (lds_ok) {
        for (int j = threadIdx.x; j < ne; j += 256)
            eld[j] = ecol[estart + j];
    }
    __syncthreads();

    int lr = threadIdx.x >> 3;          // local row 0..31
    int q  = threadIdx.x & 7;           // feature pair index
    int r  = r0 + lr;
    if (r >= n) return;
    int e0 = rowptr[r], e1 = rowptr[r + 1];
    float ax0=0,ay0=0, ax1=0,ay1=0, ax2=0,ay2=0, ax3=0,ay3=0;

    if (lds_ok) {
        int le = e0 - estart, le1 = e1 - estart;
        for (; le + 4 <= le1; le += 4) {
            u32 s0 = eld[le], s1 = eld[le+1], s2 = eld[le+2], s3 = eld[le+3];
            ushort2 v0 = *((const ushort2*)(in + (size_t)s0 * 16) + q);
            ushort2 v1 = *((const ushort2*)(in + (size_t)s1 * 16) + q);
            ushort2 v2 = *((const ushort2*)(in + (size_t)s2 * 16) + q);
            ushort2 v3 = *((const ushort2*)(in + (size_t)s3 * 16) + q);
            ax0 += bf2f(v0.x); ay0 += bf2f(v0.y);
            ax1 += bf2f(v1.x); ay1 += bf2f(v1.y);
            ax2 += bf2f(v2.x); ay2 += bf2f(v2.y);
            ax3 += bf2f(v3.x); ay3 += bf2f(v3.y);
        }
        for (; le < le1; ++le) {
            ushort2 v0 = *((const ushort2*)(in + (size_t)eld[le] * 16) + q);
            ax0 += bf2f(v0.x); ay0 += bf2f(v0.y);
        }
    } else {
        int e = e0;
        for (; e + 4 <= e1; e += 4) {
            u32 s0 = ecol[e], s1 = ecol[e+1], s2 = ecol[e+2], s3 = ecol[e+3];
            ushort2 v0 = *((const ushort2*)(in + (size_t)s0 * 16) + q);
            ushort2 v1 = *((const ushort2*)(in + (size_t)s1 * 16) + q);
            ushort2 v2 = *((const ushort2*)(in + (size_t)s2 * 16) + q);
            ushort2 v3 = *((const ushort2*)(in + (size_t)s3 * 16) + q);
            ax0 += bf2f(v0.x); ay0 += bf2f(v0.y);
            ax1 += bf2f(v1.x); ay1 += bf2f(v1.y);
            ax2 += bf2f(v2.x); ay2 += bf2f(v2.y);
            ax3 += bf2f(v3.x); ay3 += bf2f(v3.y);
        }
        for (; e < e1; ++e) {
            ushort2 v0 = *((const ushort2*)(in + (size_t)ecol[e] * 16) + q);
            ax0 += bf2f(v0.x); ay0 += bf2f(v0.y);
        }
    }

    float Sx = (ax0 + ax1) + (ax2 + ax3);
    float Sy = (ay0 + ay1) + (ay2 + ay3);
    float d1 = dis[r];
    float sc1 = sq1 ? d1 * d1 : d1;
    float Ax = Sx * sc1, Ay = Sy * sc1;
    if (addsrc) {
        ushort2 s = *((const ushort2*)(addsrc + (size_t)r * 16) + q);
        Ax += bf2f(s.x); Ay += bf2f(s.y);
    }
    if (b) {
        Ax += b[2 * q];
        Ay += b[2 * q + 1];
    }
    if (relu) {
        Ax = fmaxf(Ax, 0.f);
        Ay = fmaxf(Ay, 0.f);
    }
    ushort2 o; o.x = f2bf(Ax); o.y = f2bf(Ay);
    *((ushort2*)(out1 + (size_t)r * 16) + q) = o;
    if (out2) {
        ushort2 o2; o2.x = f2bf(Ax * d1); o2.y = f2bf(Ay * d1);
        *((ushort2*)(out2 + (size_t)r * 16) + q) = o2;
    }
}

// ---- GEMM2 (tiled, bf16 planes in, fp32 out): out = cat(P0..P3) @ W2cat + b2 ----
__global__ __launch_bounds__(256) void gemm2_bf_kernel(
    const u16* __restrict__ zb, const float* __restrict__ W2,
    const float* __restrict__ b2, float* __restrict__ out, int n, int nstride)
{
    __shared__ float As[64 * 132];
    __shared__ float Bs[64 * 64];
    const int t  = threadIdx.x;
    const int tx = t & 15;
    const int ty = t >> 4;
    const int c  = t & 15;
    const int g  = t >> 4;
    const int block_row = blockIdx.x * 128;

    float acc[8][4];
    #pragma unroll
    for (int i = 0; i < 8; ++i)
        #pragma unroll
        for (int j = 0; j < 4; ++j) acc[i][j] = 0.f;

    #pragma unroll
    for (int i = 0; i < 8; ++i) {
        int row  = g + 16 * i;
        int grow = block_row + row;
        float v0 = 0.f, v1 = 0.f, v2 = 0.f, v3 = 0.f;
        if (grow < n) {
            const u16* zp = zb + (long)grow * 16 + c;
            v0 = bf2f(zp[0]);
            v1 = bf2f(zp[(long)nstride]);
            v2 = bf2f(zp[2 * (long)nstride]);
            v3 = bf2f(zp[3 * (long)nstride]);
        }
        As[(c +  0) * 132 + row] = v0;
        As[(c + 16) * 132 + row] = v1;
        As[(c + 32) * 132 + row] = v2;
        As[(c + 48) * 132 + row] = v3;
    }
    #pragma unroll
    for (int i2 = 0; i2 < 4; ++i2) {
        int j = g + 16 * i2;
        float4 wv = *(const float4*)(W2 + j * 64 + 4 * c);
        *(float4*)(Bs + j * 64 + 4 * c) = wv;
    }
    __syncthreads();
    #pragma unroll 4
    for (int kk = 0; kk < 64; ++kk) {
        float4 a0 = *(const float4*)(As + kk * 132 + 8 * ty);
        float4 a1 = *(const float4*)(As + kk * 132 + 8 * ty + 4);
        float4 bv = *(const float4*)(Bs + kk * 64 + 4 * tx);
        float ar[8] = {a0.x, a0.y, a0.z, a0.w, a1.x, a1.y, a1.z, a1.w};
        float br[4] = {bv.x, bv.y, bv.z, bv.w};
        #pragma unroll
        for (int i = 0; i < 8; ++i)
            #pragma unroll
            for (int j = 0; j < 4; ++j)
                acc[i][j] += ar[i] * br[j];
    }
    float4 bias = *(const float4*)(b2 + 4 * tx);
    #pragma unroll
    for (int i = 0; i < 8; ++i) {
        int grow = block_row + 8 * ty + i;
        if (grow < n) {
            float4 o = make_float4(acc[i][0] + bias.x, acc[i][1] + bias.y,
                                   acc[i][2] + bias.z, acc[i][3] + bias.w);
            *(float4*)(out + (long)grow * 64 + 4 * tx) = o;
        }
    }
}

// ================= fp32 fallback path (small workspace or huge n) =================
__global__ void deg_kernel(const int* __restrict__ dst, float* __restrict__ deg, int E) {
    int e = blockIdx.x * blockDim.x + threadIdx.x;
    if (e < E) atomicAdd(&deg[dst[e]], 1.0f);
}
__global__ void disf_kernel(float* __restrict__ deg, int n) {
    int i = blockIdx.x * blockDim.x + threadIdx.x;
    if (i < n) {
        float d = deg[i];
        deg[i] = (d > 0.0f) ? rsqrtf(d) : 0.0f;
    }
}
__global__ __launch_bounds__(256) void gemm1_f32_kernel(
    const float* __restrict__ x, const float* __restrict__ W1,
    float* __restrict__ z, int n, int nstride)
{
    __shared__ float As[64 * 132];
    __shared__ float Bs[64 * 64];
    __shared__ float sums[128];
    const int t  = threadIdx.x;
    const int tx = t & 15;
    const int ty = t >> 4;
    const int c  = t & 15;
    const int g  = t >> 4;
    const int block_row = blockIdx.x * 128;
    float acc[8][4];
    #pragma unroll
    for (int i = 0; i < 8; ++i)
        #pragma unroll
        for (int j = 0; j < 4; ++j) acc[i][j] = 0.f;
    for (int kp = 0; kp < 2; ++kp) {
        #pragma unroll
        for (int i = 0; i < 8; ++i) {
            int row  = g + 16 * i;
            int grow = block_row + row;
            float v0 = 0.f, v1 = 0.f, v2 = 0.f, v3 = 0.f;
            if (grow < n) {
                const float* xp = x + (long)grow * 128 + kp * 64 + c;
                v0 = xp[0]; v1 = xp[16]; v2 = xp[32]; v3 = xp[48];
            }
            As[(c +  0) * 132 + row] = v0;
            As[(c + 16) * 132 + row] = v1;
            As[(c + 32) * 132 + row] = v2;
            As[(c + 48) * 132 + row] = v3;
            float red = (v0 + v1) + (v2 + v3);
            #pragma unroll
            for (int off = 8; off > 0; off >>= 1) red += __shfl_down(red, off, 16);
            if (c == 0) { if (kp == 0) sums[row] = red; else sums[row] += red; }
        }
        #pragma unroll
        for (int i2 = 0; i2 < 4; ++i2) {
            int kk = g + 16 * i2;
            int kglob = kp * 64 + kk;
            float4 wv = *(const float4*)(W1 + (c >> 2) * 2048 + kglob * 16 + 4 * (c & 3));
            *(float4*)(Bs + kk * 64 + 4 * c) = wv;
        }
        __syncthreads();
        #pragma unroll 4
        for (int kk = 0; kk < 64; ++kk) {
            float4 a0 = *(const float4*)(As + kk * 132 + 8 * ty);
            float4 a1 = *(const float4*)(As + kk * 132 + 8 * ty + 4);
            float4 bv = *(const float4*)(Bs + kk * 64 + 4 * tx);
            float ar[8] = {a0.x, a0.y, a0.z, a0.w, a1.x, a1.y, a1.z, a1.w};
            float br[4] = {bv.x, bv.y, bv.z, bv.w};
            #pragma unroll
            for (int i = 0; i < 8; ++i)
                #pragma unroll
                for (int j = 0; j < 4; ++j)
                    acc[i][j] += ar[i] * br[j];
        }
        __syncthreads();
    }
    int plane = tx >> 2;
    int oo4   = 4 * (tx & 3);
    #pragma unroll
    for (int i = 0; i < 8; ++i) {
        int row  = 8 * ty + i;
        int grow = block_row + row;
        if (grow < n) {
            float s = 1.0f / fmaxf(sums[row], 1e-8f);
            float4 o = make_float4(acc[i][0] * s, acc[i][1] * s, acc[i][2] * s, acc[i][3] * s);
            *(float4*)(z + (long)plane * nstride + (long)grow * 16 + oo4) = o;
        }
    }
}
__global__ __launch_bounds__(256) void spmm_atomic_kernel(
    const float* __restrict__ in, float* __restrict__ out,
    const int* __restrict__ src, const int* __restrict__ dst,
    const float* __restrict__ dis, int E)
{
    int t = blockIdx.x * blockDim.x + threadIdx.x;
    int e = t >> 4, f = t & 15;
    if (e < E) {
        int s = src[e], d = dst[e];
        atomicAdd(&out[d * 16 + f], dis[s] * dis[d] * in[s * 16 + f]);
    }
}
__global__ void bias_relu_kernel(float* __restrict__ z0, const float* __restrict__ b, int total) {
    int i = blockIdx.x * blockDim.x + threadIdx.x;
    if (i < total) {
        float v = z0[i] + b[i & 15];
        z0[i] = v > 0.0f ? v : 0.0f;
    }
}
__global__ __launch_bounds__(256) void gemm2_f32_kernel(
    const float* __restrict__ z, const float* __restrict__ W2,
    const float* __restrict__ b2, float* __restrict__ out, int n, int nstride)
{
    __shared__ float As[64 * 132];
    __shared__ float Bs[64 * 64];
    const int t  = threadIdx.x;
    const int tx = t & 15;
    const int ty = t >> 4;
    const int c  = t & 15;
    const int g  = t >> 4;
    const int block_row = blockIdx.x * 128;
    float acc[8][4];
    #pragma unroll
    for (int i = 0; i < 8; ++i)
        #pragma unroll
        for (int j = 0; j < 4; ++j) acc[i][j] = 0.f;
    #pragma unroll
    for (int i = 0; i < 8; ++i) {
        int row  = g + 16 * i;
        int grow = block_row + row;
        float v0 = 0.f, v1 = 0.f, v2 = 0.f, v3 = 0.f;
        if (grow < n) {
            const float* zp = z + (long)grow * 16 + c;
            v0 = zp[0];
            v1 = zp[(long)nstride];
            v2 = zp[2 * (long)nstride];
            v3 = zp[3 * (long)nstride];
        }
        As[(c +  0) * 132 + row] = v0;
        As[(c + 16) * 132 + row] = v1;
        As[(c + 32) * 132 + row] = v2;
        As[(c + 48) * 132 + row] = v3;
    }
    #pragma unroll
    for (int i2 = 0; i2 < 4; ++i2) {
        int j = g + 16 * i2;
        float4 wv = *(const float4*)(W2 + j * 64 + 4 * c);
        *(float4*)(Bs + j * 64 + 4 * c) = wv;
    }
    __syncthreads();
    #pragma unroll 4
    for (int kk = 0; kk < 64; ++kk) {
        float4 a0 = *(const float4*)(As + kk * 132 + 8 * ty);
        float4 a1 = *(const float4*)(As + kk * 132 + 8 * ty + 4);
        float4 bv = *(const float4*)(Bs + kk * 64 + 4 * tx);
        float ar[8] = {a0.x, a0.y, a0.z, a0.w, a1.x, a1.y, a1.z, a1.w};
        float br[4] = {bv.x, bv.y, bv.z, bv.w};
        #pragma unroll
        for (int i = 0; i < 8; ++i)
            #pragma unroll
            for (int j = 0; j < 4; ++j)
                acc[i][j] += ar[i] * br[j];
    }
    float4 bias = *(const float4*)(b2 + 4 * tx);
    #pragma unroll
    for (int i = 0; i < 8; ++i) {
        int grow = block_row + 8 * ty + i;
        if (grow < n) {
            float4 o = make_float4(acc[i][0] + bias.x, acc[i][1] + bias.y,
                                   acc[i][2] + bias.z, acc[i][3] + bias.w);
            *(float4*)(out + (long)grow * 64 + 4 * tx) = o;
        }
    }
}

static inline size_t align16(size_t v) { return (v + 15) & ~(size_t)15; }

extern "C" void kernel_launch(void* const* d_in, const int* in_sizes, int n_in,
                              void* d_out, int out_size, void* d_ws, size_t ws_size,
                              hipStream_t stream) {
    const float* x   = (const float*)d_in[0];
    const int*   ei  = (const int*)d_in[1];
    const float* W1  = (const float*)d_in[2];
    const float* b1  = (const float*)d_in[3];
    const float* W2  = (const float*)d_in[4];
    const float* bb2 = (const float*)d_in[5];
    float* out = (float*)d_out;

    const int n  = in_sizes[0] / 128;   // 50000
    const int E  = in_sizes[1] / 2;     // 800000
    const int NS = n * 16;

    const int* srcp = ei;
    const int* dstp = ei + E;

    const int nbuck = (n + BKT_SIZE - 1) >> BKT_SHIFT;
    const int nbA   = (E + CHUNK - 1) / CHUNK;
    const int m     = nbuck * nbA;
    const int nbS   = (m + 255) / 256;

    char* wsb = (char*)d_ws;
    // bytes: hist[m] | hofs[m+1] | bsum[1024] | rowptr[n+1] | dis[n] | zb[6*NS u16] | bucketed[E i2] | ecol[E u32]
    int*   hist   = (int*)wsb;
    int*   hofs   = (int*)(wsb + (size_t)4 * m);
    int*   bsum   = (int*)(wsb + (size_t)4 * (2 * m + 1));
    int*   rowptr = (int*)(wsb + (size_t)4 * (2 * m + 1 + 1024));
    float* dis    = (float*)(wsb + (size_t)4 * (2 * m + 1 + 1024 + n + 1));
    size_t zoffb  = align16((size_t)4 * (2 * m + 1 + 1024 + 2 * n + 1));
    u16*   zb     = (u16*)(wsb + zoffb);
    size_t bkoff  = align16(zoffb + (size_t)2 * 6 * NS);
    int2*  bucketed = (int2*)(wsb + bkoff);
    size_t ecooff = align16(bkoff + (size_t)8 * E);
    u32*   ecol   = (u32*)(wsb + ecooff);
    size_t need   = ecooff + (size_t)4 * E;

    int gemm_blocks = (n + 127) / 128;
    u16 *P0 = zb, *P1 = zb + NS, *P2 = zb + 2 * NS, *P3 = zb + 3 * NS;
    u16 *T0 = zb + 4 * NS, *T1 = zb + 5 * NS;

    if (ws_size >= need && nbuck <= 512 && nbS <= 1024) {
        // ---------- LDS-bucket CSR build (zero global atomics, no weights) ----------
        hist_kernel<<<nbA, 256, 0, stream>>>(dstp, hist, E, nbA, nbuck);
        scanA_kernel<<<nbS, 256, 0, stream>>>(hist, hofs, bsum, m);
        scanB_kernel<<<1, 1024, 0, stream>>>(bsum, nbS);
        scanC_kernel<<<nbS, 256, 0, stream>>>(hofs, bsum, m);
        bucket_scatter_kernel<<<nbA, 256, 0, stream>>>(srcp, dstp, hofs, bucketed, E, nbA, nbuck);
        csr_finalize_kernel<<<nbuck, 256, 0, stream>>>(bucketed, hofs, rowptr, dis, ecol, E, nbA, nbuck, n);

        gemm1_bf_kernel<<<gemm_blocks, 256, 0, stream>>>(x, W1, dis, zb, n, NS);

        int sb = (n + SPMM_ROWS - 1) / SPMM_ROWS;
        // L1 Horner (tilde space: scale1 = dis^2 = 1/deg)
        spmm_csr_bf_kernel<<<sb, 256, 0, stream>>>(P3, P2, P2, nullptr, rowptr, ecol, dis, nullptr, 0, 1, n);
        spmm_csr_bf_kernel<<<sb, 256, 0, stream>>>(P2, P1, P1, nullptr, rowptr, ecol, dis, nullptr, 0, 1, n);
        // h1 = relu(z0 + dis*S + b1); T0 = dis*h1
        spmm_csr_bf_kernel<<<sb, 256, 0, stream>>>(P1, P0, P0, T0, rowptr, ecol, dis, b1, 1, 0, n);
        // L2 hops: g_k = dis*S (gemm2 input), tilde copy = dis*g_k
        spmm_csr_bf_kernel<<<sb, 256, 0, stream>>>(T0, nullptr, P1, T1, rowptr, ecol, dis, nullptr, 0, 0, n);
        spmm_csr_bf_kernel<<<sb, 256, 0, stream>>>(T1, nullptr, P2, T0, rowptr, ecol, dis, nullptr, 0, 0, n);
        spmm_csr_bf_kernel<<<sb, 256, 0, stream>>>(T0, nullptr, P3, nullptr, rowptr, ecol, dis, nullptr, 0, 0, n);

        gemm2_bf_kernel<<<gemm_blocks, 256, 0, stream>>>(zb, W2, bb2, out, n, NS);
    } else {
        // ---------- fp32 atomic fallback ----------
        float* ws = (float*)d_ws;
        float* dis2 = ws;
        size_t z2off = ((size_t)n + 3) & ~(size_t)3;
        float* z2 = ws + z2off;
        hipMemsetAsync(dis2, 0, n * sizeof(float), stream);
        deg_kernel<<<(E + 255) / 256, 256, 0, stream>>>(dstp, dis2, E);
        disf_kernel<<<(n + 255) / 256, 256, 0, stream>>>(dis2, n);
        gemm1_f32_kernel<<<gemm_blocks, 256, 0, stream>>>(x, W1, z2, n, NS);
        int sb = (16 * E + 255) / 256;
        spmm_atomic_kernel<<<sb, 256, 0, stream>>>(z2 + 3 * NS, z2 + 2 * NS, srcp, dstp, dis2, E);
        spmm_atomic_kernel<<<sb, 256, 0, stream>>>(z2 + 2 * NS, z2 + 1 * NS, srcp, dstp, dis2, E);
        spmm_atomic_kernel<<<sb, 256, 0, stream>>>(z2 + 1 * NS, z2,          srcp, dstp, dis2, E);
        bias_relu_kernel<<<(NS + 255) / 256, 256, 0, stream>>>(z2, b1, NS);
        hipMemsetAsync(z2 + NS, 0, (size_t)3 * NS * sizeof(float), stream);
        spmm_atomic_kernel<<<sb, 256, 0, stream>>>(z2,          z2 + NS,     srcp, dstp, dis2, E);
        spmm_atomic_kernel<<<sb, 256, 0, stream>>>(z2 + NS,     z2 + 2 * NS, srcp, dstp, dis2, E);
        spmm_atomic_kernel<<<sb, 256, 0, stream>>>(z2 + 2 * NS, z2 + 3 * NS, srcp, dstp, dis2, E);
        gemm2_f32_kernel<<<gemm_blocks, 256, 0, stream>>>(z2, W2, bb2, out, n, NS);
    }
}